// Round 13
// baseline (1347.037 us; speedup 1.0000x reference)
//
#include <hip/hip_runtime.h>
#include <math.h>

#define NN 10000
#define EE 320000
#define GG 32
#define LL 6
#define TABN 2048
#define TABB (TABN / 64)
#define DTAB 5.45f
#define DCUT 5.4f
#define NCELL 512
#define CHUNK 1250  // NN/8 nodes per XCD chunk

__device__ __forceinline__ float fsilu(float x) { return x / (1.0f + __expf(-x)); }
__device__ __forceinline__ float fgelu(float x) {
  float y = 0.7978845608f * (x + 0.044715f * x * x * x);
  float t = 1.0f - 2.0f / (__expf(2.0f * y) + 1.0f);
  return 0.5f * x * (1.0f + t);
}
__device__ __forceinline__ int cell_of(const float* __restrict__ pos, int n) {
  int cx = (int)((pos[n * 3 + 0] + 12.f) * (8.f / 24.f));
  int cy = (int)((pos[n * 3 + 1] + 12.f) * (8.f / 24.f));
  int cz = (int)((pos[n * 3 + 2] + 12.f) * (8.f / 24.f));
  cx = min(7, max(0, cx)); cy = min(7, max(0, cy)); cz = min(7, max(0, cz));
  return (cx << 6) | (cy << 3) | cz;
}

// ---------------- node spatial bucket sort ----------------
__global__ void k_ncell(const float* __restrict__ pos, int* __restrict__ cnt) {
  int n = blockIdx.x * blockDim.x + threadIdx.x;
  if (n < NN) atomicAdd(&cnt[cell_of(pos, n)], 1);
}

__global__ void k_nscatter(const float* __restrict__ pos, const int* __restrict__ coff,
                           int* __restrict__ ccur, int* __restrict__ nperm,
                           int* __restrict__ ninv) {
  int n = blockIdx.x * blockDim.x + threadIdx.x;
  if (n >= NN) return;
  int c = cell_of(pos, n);
  int p = atomicAdd(&ccur[c], 1);
  int newid = coff[c] + p;
  nperm[newid] = n;
  ninv[n] = newid;
}

// ---------------- CSR build (new node ids) ----------------
__global__ void k_hist(const int* __restrict__ dst, const int* __restrict__ ninv,
                       int* __restrict__ deg) {
  int e = blockIdx.x * blockDim.x + threadIdx.x;
  if (e < EE) atomicAdd(&deg[ninv[dst[e]]], 1);
}

__global__ void k_scan(const int* __restrict__ cnt, int* __restrict__ off, int n) {
  __shared__ int sm[1024];
  __shared__ int carry_s;
  if (threadIdx.x == 0) { carry_s = 0; off[0] = 0; }
  __syncthreads();
  for (int base = 0; base < n; base += 1024) {
    int i = base + (int)threadIdx.x;
    int v = (i < n) ? cnt[i] : 0;
    sm[threadIdx.x] = v;
    __syncthreads();
    for (int o = 1; o < 1024; o <<= 1) {
      int t = (threadIdx.x >= o) ? sm[threadIdx.x - o] : 0;
      __syncthreads();
      sm[threadIdx.x] += t;
      __syncthreads();
    }
    if (i < n) off[i + 1] = carry_s + sm[threadIdx.x];
    __syncthreads();
    if (threadIdx.x == 0) carry_s += sm[1023];
    __syncthreads();
  }
}

__global__ void k_scatter(const int* __restrict__ dst, const int* __restrict__ ninv,
                          const int* __restrict__ row_off, int* __restrict__ cursor,
                          int* __restrict__ perm) {
  int e = blockIdx.x * blockDim.x + threadIdx.x;
  if (e < EE) {
    int d = ninv[dst[e]];
    int p = atomicAdd(&cursor[d], 1);
    perm[row_off[d] + p] = e;
  }
}

// ---------------- distances in CSR order ----------------
__global__ void k_geom_d(const float* __restrict__ pos, const int* __restrict__ esrc,
                         const int* __restrict__ edst, const int* __restrict__ perm,
                         float* __restrict__ d_csr) {
  int j = blockIdx.x * blockDim.x + threadIdx.x;
  if (j >= EE) return;
  int e = perm[j];
  int s = esrc[e], dd = edst[e];
  float rx = pos[dd * 3 + 0] - pos[s * 3 + 0];
  float ry = pos[dd * 3 + 1] - pos[s * 3 + 1];
  float rz = pos[dd * 3 + 2] - pos[s * 3 + 2];
  d_csr[j] = sqrtf(rx * rx + ry * ry + rz * rz + 1e-6f);
}

// ---------------- active-edge list (d < DCUT) ----------------
__global__ void k_act_cnt(const int* __restrict__ row_off, const float* __restrict__ d_csr,
                          int* __restrict__ acnt) {
  int n = blockIdx.x * blockDim.x + threadIdx.x;
  if (n >= NN) return;
  int c = 0;
  for (int j = row_off[n]; j < row_off[n + 1]; ++j) c += (d_csr[j] < DCUT) ? 1 : 0;
  acnt[n] = c;
}

__global__ void k_act_fill(const int* __restrict__ row_off, const float* __restrict__ d_csr,
                           const int* __restrict__ act_off, int* __restrict__ act_idx) {
  int n = blockIdx.x * blockDim.x + threadIdx.x;
  if (n >= NN) return;
  int a = act_off[n];
  for (int j = row_off[n]; j < row_off[n + 1]; ++j)
    if (d_csr[j] < DCUT) act_idx[a++] = j;
}

// ---------------- compacted geometry per active edge (src as new id) ----------------
__global__ void k_geom_act(const int* __restrict__ act_idx, const int* __restrict__ perm,
                           const int* __restrict__ esrc, const int* __restrict__ edst,
                           const int* __restrict__ ninv, const float* __restrict__ pos,
                           const int* __restrict__ act_off, float* __restrict__ d_a,
                           int* __restrict__ src_a, float* __restrict__ sh_a) {
  int a = blockIdx.x * blockDim.x + threadIdx.x;
  if (a >= act_off[NN]) return;
  int j = act_idx[a];
  int e = perm[j];
  int s = esrc[e], dd = edst[e];
  float rx = pos[dd * 3 + 0] - pos[s * 3 + 0];
  float ry = pos[dd * 3 + 1] - pos[s * 3 + 1];
  float rz = pos[dd * 3 + 2] - pos[s * 3 + 2];
  float d = sqrtf(rx * rx + ry * ry + rz * rz + 1e-6f);
  float inv = 1.0f / d;
  float x = rx * inv, y = ry * inv, z = rz * inv;
  d_a[a] = d;
  src_a[a] = ninv[s];
  const float s3 = 1.7320508075688772f;
  const float s5 = 2.23606797749979f;
  const float s15 = 3.872983346207417f;
  sh_a[a * 8 + 0] = s3 * x;
  sh_a[a * 8 + 1] = s3 * y;
  sh_a[a * 8 + 2] = s3 * z;
  sh_a[a * 8 + 3] = s15 * x * y;
  sh_a[a * 8 + 4] = s15 * y * z;
  sh_a[a * 8 + 5] = 0.5f * s5 * (3.0f * z * z - 1.0f);
  sh_a[a * 8 + 6] = s15 * x * z;
  sh_a[a * 8 + 7] = 0.5f * s15 * (x * x - y * y);
}

// ---------------- radial MLP table w(d) (all layers) ----------------
__global__ void k_build_wtab(const float* __restrict__ Wrad1, const float* __restrict__ brad1,
                             const float* __restrict__ Wrad2, const float* __restrict__ brad2,
                             float* __restrict__ wtab) {
  int l = blockIdx.x / TABB;
  int blk = blockIdx.x % TABB;
  __shared__ float W1[128 * 64];
  __shared__ float W2[64 * 64];
  __shared__ float b1[64], b2[64];
  __shared__ float rbf_s[4][128];
  __shared__ float h_s[4][64];
  const float* w1p = Wrad1 + (size_t)l * 128 * 64;
  const float* w2p = Wrad2 + (size_t)l * 64 * 64;
  for (int i = threadIdx.x; i < 128 * 64; i += 256) W1[i] = w1p[i];
  for (int i = threadIdx.x; i < 64 * 64; i += 256) W2[i] = w2p[i];
  if (threadIdx.x < 64) {
    b1[threadIdx.x] = brad1[(size_t)l * 64 + threadIdx.x];
    b2[threadIdx.x] = brad2[(size_t)l * 64 + threadIdx.x];
  }
  __syncthreads();
  int wv = threadIdx.x >> 6, lane = threadIdx.x & 63;
  const float width = 5.0f / 128.0f;
  for (int k = wv; k < 64; k += 4) {
    int i = blk * 64 + k;
    float d = (float)i * (DTAB / (float)(TABN - 1));
    float c0 = (5.0f * (float)lane) / 127.0f;
    float c1 = (5.0f * (float)(lane + 64)) / 127.0f;
    float t0 = (d - c0) / width, t1 = (d - c1) / width;
    rbf_s[wv][lane] = __expf(-0.5f * t0 * t0);
    rbf_s[wv][lane + 64] = __expf(-0.5f * t1 * t1);
    float acc = b1[lane];
    #pragma unroll 8
    for (int i2 = 0; i2 < 128; i2++) acc += rbf_s[wv][i2] * W1[i2 * 64 + lane];
    acc = fsilu(acc);
    h_s[wv][lane] = acc;
    float acc2 = b2[lane];
    #pragma unroll 8
    for (int i2 = 0; i2 < 64; i2++) acc2 += h_s[wv][i2] * W2[i2 * 64 + lane];
    wtab[((size_t)l * TABN + i) * 64 + lane] = fsilu(acc2);
  }
}

// ---------------- product tables: gs = w@Ww_s (128 cols) ----------------
__global__ __launch_bounds__(256) void k_build_gs(
    const float* __restrict__ wtab, const float* __restrict__ Ww_s,
    float* __restrict__ gs_tab) {
  int l = blockIdx.x / TABB, blk = blockIdx.x % TABB;
  __shared__ float W[64 * 128];
  __shared__ float ws[64][65];
  const float* wp = Ww_s + (size_t)l * 64 * 128;
  for (int i = threadIdx.x; i < 64 * 128; i += 256) W[i] = wp[i];
  const float* wt = wtab + ((size_t)l * TABN + blk * 64) * 64;
  for (int i = threadIdx.x; i < 64 * 64; i += 256) ws[i >> 6][i & 63] = wt[i];
  __syncthreads();
  int col = threadIdx.x & 127, eg = threadIdx.x >> 7;
  for (int e0 = 0; e0 < 64; e0 += 2) {
    int e = e0 + eg;
    float acc = 0.f;
    #pragma unroll 8
    for (int i = 0; i < 64; i++) acc += ws[e][i] * W[i * 128 + col];
    gs_tab[((size_t)l * TABN + blk * 64 + e) * 128 + col] = acc;
  }
}

// ---------------- product tables: gv pairs (w@Ww_v, w@Ww_vv) ----------------
__global__ __launch_bounds__(256) void k_build_gv(
    const float* __restrict__ wtab, const float* __restrict__ Ww_v,
    const float* __restrict__ Ww_vv, float* __restrict__ gv_tab) {
  int l = blockIdx.x / TABB, blk = blockIdx.x % TABB;
  __shared__ float W[64 * 128];  // interleaved pairs
  __shared__ float ws[64][65];
  const float* wv_p = Ww_v + (size_t)l * 64 * 64;
  const float* wvv_p = Ww_vv + (size_t)l * 64 * 64;
  for (int i = threadIdx.x; i < 64 * 128; i += 256) {
    int r = i >> 7, cc = i & 127;
    int c = cc >> 1;
    W[i] = (cc & 1) ? wvv_p[r * 64 + c] : wv_p[r * 64 + c];
  }
  const float* wt = wtab + ((size_t)l * TABN + blk * 64) * 64;
  for (int i = threadIdx.x; i < 64 * 64; i += 256) ws[i >> 6][i & 63] = wt[i];
  __syncthreads();
  int col = threadIdx.x & 127, eg = threadIdx.x >> 7;
  for (int e0 = 0; e0 < 64; e0 += 2) {
    int e = e0 + eg;
    float acc = 0.f;
    #pragma unroll 8
    for (int i = 0; i < 64; i++) acc += ws[e][i] * W[i * 128 + col];
    gv_tab[((size_t)l * TABN + blk * 64 + e) * 128 + col] = acc;
  }
}

// ---------------- product tables: gt pairs (w@Ww_t, w@Ww_tt) ----------------
__global__ __launch_bounds__(256) void k_build_gt(
    const float* __restrict__ wtab, const float* __restrict__ Ww_t,
    const float* __restrict__ Ww_tt, float* __restrict__ gt_tab) {
  int l = blockIdx.x / TABB, blk = blockIdx.x % TABB;
  __shared__ float W[64 * 64];  // interleaved pairs
  __shared__ float ws[64][65];
  const float* wt_p = Ww_t + (size_t)l * 64 * 32;
  const float* wtt_p = Ww_tt + (size_t)l * 64 * 32;
  for (int i = threadIdx.x; i < 64 * 64; i += 256) {
    int r = i >> 6, cc = i & 63;
    int c = cc >> 1;
    W[i] = (cc & 1) ? wtt_p[r * 32 + c] : wt_p[r * 32 + c];
  }
  const float* wt = wtab + ((size_t)l * TABN + blk * 64) * 64;
  for (int i = threadIdx.x; i < 64 * 64; i += 256) ws[i >> 6][i & 63] = wt[i];
  __syncthreads();
  int col = threadIdx.x & 63, eg = threadIdx.x >> 6;
  for (int e0 = 0; e0 < 64; e0 += 4) {
    int e = e0 + eg;
    float acc = 0.f;
    #pragma unroll 8
    for (int i = 0; i < 64; i++) acc += ws[e][i] * W[i * 64 + col];
    gt_tab[((size_t)l * TABN + blk * 64 + e) * 64 + col] = acc;
  }
}

// ---------------- init s (gather via nperm) ----------------
__global__ void k_init_s(const int* __restrict__ node_atom, const int* __restrict__ nperm,
                         const float* __restrict__ atom_emb, float* __restrict__ s) {
  int i = blockIdx.x * blockDim.x + threadIdx.x;
  if (i < NN * 128) {
    int n = i >> 7, c = i & 127;
    s[i] = atom_emb[node_atom[nperm[n]] * 128 + c];
  }
}

// ---------------- node transforms, 16 nodes/block ----------------
__global__ __launch_bounds__(256) void k_node_tf(
    const float* __restrict__ s, const float* __restrict__ v, const float* __restrict__ t,
    const float* __restrict__ Ws_src, const float* __restrict__ Ws_v,
    const float* __restrict__ Ws_t, const float* __restrict__ Wv_v,
    const float* __restrict__ Wt_t,
    float* __restrict__ sWsrc, float* __restrict__ sWv,
    float* __restrict__ sWt, float* __restrict__ vW, float* __restrict__ tW) {
  int nb = blockIdx.x * 16;
  int tid = threadIdx.x;
  __shared__ float s16[16][129];
  __shared__ float v16[16][192];
  __shared__ float t16[16][160];
  for (int idx = tid; idx < 16 * 128; idx += 256) {
    int n = idx >> 7, c = idx & 127;
    s16[n][c] = s[(size_t)(nb + n) * 128 + c];
  }
  for (int idx = tid; idx < 16 * 192; idx += 256) {
    int n = idx / 192, c = idx % 192;
    v16[n][c] = v[(size_t)(nb + n) * 192 + c];
  }
  for (int idx = tid; idx < 16 * 160; idx += 256) {
    int n = idx / 160, c = idx % 160;
    t16[n][c] = t[(size_t)(nb + n) * 160 + c];
  }
  __syncthreads();
  {
    int col = tid & 127, ng = tid >> 7;
    float acc[8] = {0, 0, 0, 0, 0, 0, 0, 0};
    for (int c = 0; c < 128; c++) {
      float w = Ws_src[c * 128 + col];
      #pragma unroll
      for (int n = 0; n < 8; n++) acc[n] += s16[ng * 8 + n][c] * w;
    }
    #pragma unroll
    for (int n = 0; n < 8; n++) sWsrc[(size_t)(nb + ng * 8 + n) * 128 + col] = acc[n];
  }
  {
    int col = tid & 63, ng = tid >> 6;
    float acc[4] = {0, 0, 0, 0};
    for (int c = 0; c < 128; c++) {
      float w = Ws_v[c * 64 + col];
      #pragma unroll
      for (int n = 0; n < 4; n++) acc[n] += s16[ng * 4 + n][c] * w;
    }
    #pragma unroll
    for (int n = 0; n < 4; n++) sWv[(size_t)(nb + ng * 4 + n) * 64 + col] = acc[n];
  }
  {
    int col = tid & 31, ng = tid >> 5;
    float acc[2] = {0, 0};
    for (int c = 0; c < 128; c++) {
      float w = Ws_t[c * 32 + col];
      acc[0] += s16[ng * 2 + 0][c] * w;
      acc[1] += s16[ng * 2 + 1][c] * w;
    }
    sWt[(size_t)(nb + ng * 2 + 0) * 32 + col] = acc[0];
    sWt[(size_t)(nb + ng * 2 + 1) * 32 + col] = acc[1];
  }
  {
    int dd = tid & 63, ng = tid >> 6;
    float acc[4][3] = {};
    for (int c = 0; c < 64; c++) {
      float w = Wv_v[c * 64 + dd];
      #pragma unroll
      for (int n = 0; n < 4; n++) {
        acc[n][0] += v16[ng * 4 + n][c * 3 + 0] * w;
        acc[n][1] += v16[ng * 4 + n][c * 3 + 1] * w;
        acc[n][2] += v16[ng * 4 + n][c * 3 + 2] * w;
      }
    }
    #pragma unroll
    for (int n = 0; n < 4; n++) {
      size_t b = (size_t)(nb + ng * 4 + n) * 192 + dd * 3;
      vW[b + 0] = acc[n][0];
      vW[b + 1] = acc[n][1];
      vW[b + 2] = acc[n][2];
    }
  }
  {
    int dd = tid & 31, ng = tid >> 5;
    float acc[2][5] = {};
    for (int c = 0; c < 32; c++) {
      float w = Wt_t[c * 32 + dd];
      #pragma unroll
      for (int n = 0; n < 2; n++)
        #pragma unroll
        for (int m = 0; m < 5; m++) acc[n][m] += t16[ng * 2 + n][c * 5 + m] * w;
    }
    #pragma unroll
    for (int n = 0; n < 2; n++) {
      size_t b = (size_t)(nb + ng * 2 + n) * 160 + dd * 5;
      #pragma unroll
      for (int m = 0; m < 5; m++) tW[b + m] = acc[n][m];
    }
  }
}

// ---------------- mega: single-pass online-softmax, pair unrolled, XCD swizzle ----------------
__global__ __launch_bounds__(256) void k_mega(
    const int* __restrict__ row_off, const int* __restrict__ act_off,
    const int* __restrict__ src_a, const float* __restrict__ d_a,
    const float* __restrict__ gsL, const float* __restrict__ gvL,
    const float* __restrict__ gtL, const float* __restrict__ attn_l,
    const float* __restrict__ sWsrc, const float* __restrict__ sWv,
    const float* __restrict__ sWt, const float* __restrict__ vW,
    const float* __restrict__ tW, const float* __restrict__ sh_a,
    float* __restrict__ agg_s, float* __restrict__ agg_v, float* __restrict__ agg_t) {
  int wv = threadIdx.x >> 6, lane = threadIdx.x & 63;
  int lt = lane & 31;
  // XCD-chunked swizzle: consecutive blockIdx%8 presumed round-robin across XCDs;
  // give each XCD a contiguous (spatially sorted) node chunk for L2 gather locality.
  int xcd = blockIdx.x & 7;
  int idx = blockIdx.x >> 3;
  int local = idx * 4 + wv;
  if (local >= CHUNK) return;
  int n = xcd * CHUNK + local;
  int alo = act_off[n], ahi = act_off[n + 1];
  int nact = ahi - alo;
  int ninact = (row_off[n + 1] - row_off[n]) - nact;
  const float sc = (float)(TABN - 1) / DTAB;
  float atnA = attn_l[lane];
  float atnB = attn_l[64 + lane];
  float rm0, rm1, rm2, rm3;
  rm0 = rm1 = rm2 = rm3 = (ninact > 0) ? 0.0f : -1e30f;
  float rs0 = 0.f, rs1 = 0.f, rs2 = 0.f, rs3 = 0.f;
  float as0 = 0.f, as1 = 0.f;
  float av0 = 0.f, av1 = 0.f, av2 = 0.f;
  float at0 = 0.f, at1 = 0.f, at2 = 0.f, at3 = 0.f, at4 = 0.f;
  int a = alo;
  for (; a + 1 < ahi; a += 2) {
    int aA = a, aB = a + 1;
    float dA = d_a[aA], dB = d_a[aB];
    int snA = src_a[aA], snB = src_a[aB];
    float xA = fminf(dA * sc, (float)(TABN - 1) - 1.0f);
    float xB = fminf(dB * sc, (float)(TABN - 1) - 1.0f);
    int iA = (int)xA, iB = (int)xB;
    float fA = xA - (float)iA, fB = xB - (float)iB;
    float g1A = 1.0f - fA, g1B = 1.0f - fB;
    const float* gA = gsL + (size_t)iA * 128;
    const float* gB = gsL + (size_t)iB * 128;
    float gsA_A = gA[lane] * g1A + gA[128 + lane] * fA;
    float gsB_A = gA[64 + lane] * g1A + gA[192 + lane] * fA;
    float gsA_B = gB[lane] * g1B + gB[128 + lane] * fB;
    float gsB_B = gB[64 + lane] * g1B + gB[192 + lane] * fB;
    float m0A = sWsrc[(size_t)snA * 128 + lane] * gsA_A;
    float m1A = sWsrc[(size_t)snA * 128 + 64 + lane] * gsB_A;
    float m0B = sWsrc[(size_t)snB * 128 + lane] * gsA_B;
    float m1B = sWsrc[(size_t)snB * 128 + 64 + lane] * gsB_B;
    const float* gvA = gvL + (size_t)iA * 128;
    const float* gvB = gvL + (size_t)iB * 128;
    float2 pA0 = *(const float2*)&gvA[2 * lane];
    float2 pA1 = *(const float2*)&gvA[128 + 2 * lane];
    float2 pB0 = *(const float2*)&gvB[2 * lane];
    float2 pB1 = *(const float2*)&gvB[128 + 2 * lane];
    float gavA = pA0.x * g1A + pA1.x * fA;
    float gbvA = pA0.y * g1A + pA1.y * fA;
    float gavB = pB0.x * g1B + pB1.x * fB;
    float gbvB = pB0.y * g1B + pB1.y * fB;
    float svA = sWv[(size_t)snA * 64 + lane];
    float svB = sWv[(size_t)snB * 64 + lane];
    float4 s1A = *(const float4*)&sh_a[(size_t)aA * 8];
    float4 s2A = *(const float4*)&sh_a[(size_t)aA * 8 + 4];
    float4 s1B = *(const float4*)&sh_a[(size_t)aB * 8];
    float4 s2B = *(const float4*)&sh_a[(size_t)aB * 8 + 4];
    const float* vpA = &vW[(size_t)snA * 192 + lane * 3];
    const float* vpB = &vW[(size_t)snB * 192 + lane * 3];
    float vA0 = vpA[0], vA1 = vpA[1], vA2 = vpA[2];
    float vB0 = vpB[0], vB1 = vpB[1], vB2 = vpB[2];
    float gatA = 0.f, gbtA = 0.f, gatB = 0.f, gbtB = 0.f;
    float stA = 0.f, stB = 0.f;
    float tA0 = 0.f, tA1 = 0.f, tA2 = 0.f, tA3 = 0.f, tA4 = 0.f;
    float tB0 = 0.f, tB1 = 0.f, tB2 = 0.f, tB3 = 0.f, tB4 = 0.f;
    if (lane < 32) {
      const float* gtA = gtL + (size_t)iA * 64;
      const float* gtB = gtL + (size_t)iB * 64;
      float2 qA0 = *(const float2*)&gtA[2 * lt];
      float2 qA1 = *(const float2*)&gtA[64 + 2 * lt];
      float2 qB0 = *(const float2*)&gtB[2 * lt];
      float2 qB1 = *(const float2*)&gtB[64 + 2 * lt];
      gatA = qA0.x * g1A + qA1.x * fA;
      gbtA = qA0.y * g1A + qA1.y * fA;
      gatB = qB0.x * g1B + qB1.x * fB;
      gbtB = qB0.y * g1B + qB1.y * fB;
      stA = sWt[(size_t)snA * 32 + lane];
      stB = sWt[(size_t)snB * 32 + lane];
      const float* tpA = &tW[(size_t)snA * 160 + lane * 5];
      const float* tpB = &tW[(size_t)snB * 160 + lane * 5];
      tA0 = tpA[0]; tA1 = tpA[1]; tA2 = tpA[2]; tA3 = tpA[3]; tA4 = tpA[4];
      tB0 = tpB[0]; tB1 = tpB[1]; tB2 = tpB[2]; tB3 = tpB[3]; tB4 = tpB[4];
    }
    float p01A = m0A * atnA, p23A = m1A * atnB;
    float p01B = m0B * atnA, p23B = m1B * atnB;
    #pragma unroll
    for (int mm = 1; mm < 32; mm <<= 1) {
      p01A += __shfl_xor(p01A, mm);
      p23A += __shfl_xor(p23A, mm);
      p01B += __shfl_xor(p01B, mm);
      p23B += __shfl_xor(p23B, mm);
    }
    float l0A = __shfl(p01A, 0), l1A = __shfl(p01A, 32);
    float l2A = __shfl(p23A, 0), l3A = __shfl(p23A, 32);
    float l0B = __shfl(p01B, 0), l1B = __shfl(p01B, 32);
    float l2B = __shfl(p23B, 0), l3B = __shfl(p23B, 32);
    {
      float nm0 = fmaxf(rm0, l0A), nm1 = fmaxf(rm1, l1A);
      float nm2 = fmaxf(rm2, l2A), nm3 = fmaxf(rm3, l3A);
      float f0 = __expf(rm0 - nm0), f1 = __expf(rm1 - nm1);
      float f2 = __expf(rm2 - nm2), f3 = __expf(rm3 - nm3);
      float w0 = __expf(l0A - nm0), w1 = __expf(l1A - nm1);
      float w2 = __expf(l2A - nm2), w3 = __expf(l3A - nm3);
      rm0 = nm0; rm1 = nm1; rm2 = nm2; rm3 = nm3;
      rs0 = rs0 * f0 + w0; rs1 = rs1 * f1 + w1;
      rs2 = rs2 * f2 + w2; rs3 = rs3 * f3 + w3;
      float fS0 = (lane < 32) ? f0 : f1;
      float fS1 = (lane < 32) ? f2 : f3;
      float wS0 = (lane < 32) ? w0 : w1;
      float wS1 = (lane < 32) ? w2 : w3;
      as0 = as0 * fS0 + wS0 * m0A;
      as1 = as1 * fS1 + wS1 * m1A;
      float fV = (lane < 16) ? f0 : (lane < 32) ? f1 : (lane < 48) ? f2 : f3;
      float wV = (lane < 16) ? w0 : (lane < 32) ? w1 : (lane < 48) ? w2 : w3;
      float avv = svA * gavA;
      av0 = av0 * fV + wV * (avv * s1A.x + vA0 * gbvA);
      av1 = av1 * fV + wV * (avv * s1A.y + vA1 * gbvA);
      av2 = av2 * fV + wV * (avv * s1A.z + vA2 * gbvA);
      if (lane < 32) {
        float fT = (lane < 8) ? f0 : (lane < 16) ? f1 : (lane < 24) ? f2 : f3;
        float wT = (lane < 8) ? w0 : (lane < 16) ? w1 : (lane < 24) ? w2 : w3;
        float att = stA * gatA;
        at0 = at0 * fT + wT * (att * s1A.w + tA0 * gbtA);
        at1 = at1 * fT + wT * (att * s2A.x + tA1 * gbtA);
        at2 = at2 * fT + wT * (att * s2A.y + tA2 * gbtA);
        at3 = at3 * fT + wT * (att * s2A.z + tA3 * gbtA);
        at4 = at4 * fT + wT * (att * s2A.w + tA4 * gbtA);
      }
    }
    {
      float nm0 = fmaxf(rm0, l0B), nm1 = fmaxf(rm1, l1B);
      float nm2 = fmaxf(rm2, l2B), nm3 = fmaxf(rm3, l3B);
      float f0 = __expf(rm0 - nm0), f1 = __expf(rm1 - nm1);
      float f2 = __expf(rm2 - nm2), f3 = __expf(rm3 - nm3);
      float w0 = __expf(l0B - nm0), w1 = __expf(l1B - nm1);
      float w2 = __expf(l2B - nm2), w3 = __expf(l3B - nm3);
      rm0 = nm0; rm1 = nm1; rm2 = nm2; rm3 = nm3;
      rs0 = rs0 * f0 + w0; rs1 = rs1 * f1 + w1;
      rs2 = rs2 * f2 + w2; rs3 = rs3 * f3 + w3;
      float fS0 = (lane < 32) ? f0 : f1;
      float fS1 = (lane < 32) ? f2 : f3;
      float wS0 = (lane < 32) ? w0 : w1;
      float wS1 = (lane < 32) ? w2 : w3;
      as0 = as0 * fS0 + wS0 * m0B;
      as1 = as1 * fS1 + wS1 * m1B;
      float fV = (lane < 16) ? f0 : (lane < 32) ? f1 : (lane < 48) ? f2 : f3;
      float wV = (lane < 16) ? w0 : (lane < 32) ? w1 : (lane < 48) ? w2 : w3;
      float avv = svB * gavB;
      av0 = av0 * fV + wV * (avv * s1B.x + vB0 * gbvB);
      av1 = av1 * fV + wV * (avv * s1B.y + vB1 * gbvB);
      av2 = av2 * fV + wV * (avv * s1B.z + vB2 * gbvB);
      if (lane < 32) {
        float fT = (lane < 8) ? f0 : (lane < 16) ? f1 : (lane < 24) ? f2 : f3;
        float wT = (lane < 8) ? w0 : (lane < 16) ? w1 : (lane < 24) ? w2 : w3;
        float att = stB * gatB;
        at0 = at0 * fT + wT * (att * s1B.w + tB0 * gbtB);
        at1 = at1 * fT + wT * (att * s2B.x + tB1 * gbtB);
        at2 = at2 * fT + wT * (att * s2B.y + tB2 * gbtB);
        at3 = at3 * fT + wT * (att * s2B.z + tB3 * gbtB);
        at4 = at4 * fT + wT * (att * s2B.w + tB4 * gbtB);
      }
    }
  }
  for (; a < ahi; ++a) {
    float x = d_a[a] * sc;
    x = fminf(x, (float)(TABN - 1) - 1.0f);
    int i0 = (int)x; float f = x - (float)i0; float g1 = 1.0f - f;
    int sn = src_a[a];
    const float* g0 = gsL + (size_t)i0 * 128;
    float gsA = g0[lane] * g1 + g0[128 + lane] * f;
    float gsB = g0[64 + lane] * g1 + g0[192 + lane] * f;
    float m0 = sWsrc[(size_t)sn * 128 + lane] * gsA;
    float m1 = sWsrc[(size_t)sn * 128 + 64 + lane] * gsB;
    float p01 = m0 * atnA;
    float p23 = m1 * atnB;
    #pragma unroll
    for (int mm = 1; mm < 32; mm <<= 1) {
      p01 += __shfl_xor(p01, mm);
      p23 += __shfl_xor(p23, mm);
    }
    float l0 = __shfl(p01, 0), l1 = __shfl(p01, 32);
    float l2 = __shfl(p23, 0), l3 = __shfl(p23, 32);
    float nm0 = fmaxf(rm0, l0), nm1 = fmaxf(rm1, l1);
    float nm2 = fmaxf(rm2, l2), nm3 = fmaxf(rm3, l3);
    float f0 = __expf(rm0 - nm0), f1 = __expf(rm1 - nm1);
    float f2 = __expf(rm2 - nm2), f3 = __expf(rm3 - nm3);
    float w0 = __expf(l0 - nm0), w1 = __expf(l1 - nm1);
    float w2 = __expf(l2 - nm2), w3 = __expf(l3 - nm3);
    rm0 = nm0; rm1 = nm1; rm2 = nm2; rm3 = nm3;
    rs0 = rs0 * f0 + w0; rs1 = rs1 * f1 + w1;
    rs2 = rs2 * f2 + w2; rs3 = rs3 * f3 + w3;
    float fS0 = (lane < 32) ? f0 : f1;
    float fS1 = (lane < 32) ? f2 : f3;
    float wS0 = (lane < 32) ? w0 : w1;
    float wS1 = (lane < 32) ? w2 : w3;
    as0 = as0 * fS0 + wS0 * m0;
    as1 = as1 * fS1 + wS1 * m1;
    const float* gv0 = gvL + (size_t)i0 * 128;
    float2 p0 = *(const float2*)&gv0[2 * lane];
    float2 p1 = *(const float2*)&gv0[128 + 2 * lane];
    float gav = p0.x * g1 + p1.x * f;
    float gbv = p0.y * g1 + p1.y * f;
    float fV = (lane < 16) ? f0 : (lane < 32) ? f1 : (lane < 48) ? f2 : f3;
    float wV = (lane < 16) ? w0 : (lane < 32) ? w1 : (lane < 48) ? w2 : w3;
    float avv = sWv[(size_t)sn * 64 + lane] * gav;
    float4 s1 = *(const float4*)&sh_a[(size_t)a * 8];
    float4 s2 = *(const float4*)&sh_a[(size_t)a * 8 + 4];
    const float* vp = &vW[(size_t)sn * 192 + lane * 3];
    av0 = av0 * fV + wV * (avv * s1.x + vp[0] * gbv);
    av1 = av1 * fV + wV * (avv * s1.y + vp[1] * gbv);
    av2 = av2 * fV + wV * (avv * s1.z + vp[2] * gbv);
    if (lane < 32) {
      const float* gt0 = gtL + (size_t)i0 * 64;
      float2 q0 = *(const float2*)&gt0[2 * lt];
      float2 q1 = *(const float2*)&gt0[64 + 2 * lt];
      float gat = q0.x * g1 + q1.x * f;
      float gbt = q0.y * g1 + q1.y * f;
      float fT = (lane < 8) ? f0 : (lane < 16) ? f1 : (lane < 24) ? f2 : f3;
      float wT = (lane < 8) ? w0 : (lane < 16) ? w1 : (lane < 24) ? w2 : w3;
      float att = sWt[(size_t)sn * 32 + lane] * gat;
      const float* tp = &tW[(size_t)sn * 160 + lane * 5];
      at0 = at0 * fT + wT * (att * s1.w + tp[0] * gbt);
      at1 = at1 * fT + wT * (att * s2.x + tp[1] * gbt);
      at2 = at2 * fT + wT * (att * s2.y + tp[2] * gbt);
      at3 = at3 * fT + wT * (att * s2.z + tp[3] * gbt);
      at4 = at4 * fT + wT * (att * s2.w + tp[4] * gbt);
    }
  }
  if (ninact > 0) {
    rs0 += (float)ninact * __expf(-rm0);
    rs1 += (float)ninact * __expf(-rm1);
    rs2 += (float)ninact * __expf(-rm2);
    rs3 += (float)ninact * __expf(-rm3);
  }
  float r0 = 1.0f / (rs0 + 1e-9f), r1 = 1.0f / (rs1 + 1e-9f);
  float r2 = 1.0f / (rs2 + 1e-9f), r3 = 1.0f / (rs3 + 1e-9f);
  float rS0 = (lane < 32) ? r0 : r1;
  float rS1 = (lane < 32) ? r2 : r3;
  float rV = (lane < 16) ? r0 : (lane < 32) ? r1 : (lane < 48) ? r2 : r3;
  agg_s[(size_t)n * 128 + lane] = as0 * rS0;
  agg_s[(size_t)n * 128 + 64 + lane] = as1 * rS1;
  agg_v[(size_t)n * 192 + lane * 3 + 0] = av0 * rV;
  agg_v[(size_t)n * 192 + lane * 3 + 1] = av1 * rV;
  agg_v[(size_t)n * 192 + lane * 3 + 2] = av2 * rV;
  if (lane < 32) {
    float rT = (lane < 8) ? r0 : (lane < 16) ? r1 : (lane < 24) ? r2 : r3;
    agg_t[(size_t)n * 160 + lane * 5 + 0] = at0 * rT;
    agg_t[(size_t)n * 160 + lane * 5 + 1] = at1 * rT;
    agg_t[(size_t)n * 160 + lane * 5 + 2] = at2 * rT;
    agg_t[(size_t)n * 160 + lane * 5 + 3] = at3 * rT;
    agg_t[(size_t)n * 160 + lane * 5 + 4] = at4 * rT;
  }
}

// ---------------- node update, 16 nodes/block, ping-pong LDS ----------------
__global__ __launch_bounds__(256) void k_node_up(
    float* __restrict__ s, float* __restrict__ v, float* __restrict__ t,
    const float* __restrict__ agg_s, const float* __restrict__ agg_v,
    const float* __restrict__ agg_t, const float* __restrict__ Wo_s,
    const float* __restrict__ Wo_v, const float* __restrict__ Wo_t,
    const float* __restrict__ g_s, const float* __restrict__ b_s,
    const float* __restrict__ g_v, const float* __restrict__ g_t) {
  int nb = blockIdx.x * 16;
  int tid = threadIdx.x;
  __shared__ float bin[16][193];
  __shared__ float bout[16][193];
  for (int idx = tid; idx < 16 * 128; idx += 256) {
    int n = idx >> 7, c = idx & 127;
    bin[n][c] = agg_s[(size_t)(nb + n) * 128 + c];
  }
  __syncthreads();
  {
    int col = tid & 127, ng = tid >> 7;
    float acc[8];
    #pragma unroll
    for (int n = 0; n < 8; n++) acc[n] = s[(size_t)(nb + ng * 8 + n) * 128 + col];
    for (int c = 0; c < 128; c++) {
      float w = Wo_s[c * 128 + col];
      #pragma unroll
      for (int n = 0; n < 8; n++) acc[n] += bin[ng * 8 + n][c] * w;
    }
    #pragma unroll
    for (int n = 0; n < 8; n++) bout[ng * 8 + n][col] = acc[n];
  }
  __syncthreads();
  for (int idx = tid; idx < 16 * 192; idx += 256) {
    int n = idx / 192, c = idx % 192;
    bin[n][c] = agg_v[(size_t)(nb + n) * 192 + c];
  }
  {
    int node = tid >> 4, q = tid & 15;
    float sm = 0.f, sq = 0.f;
    #pragma unroll
    for (int u = 0; u < 8; u++) {
      float x = bout[node][q * 8 + u];
      sm += x; sq += x * x;
    }
    sm += __shfl_xor(sm, 1); sq += __shfl_xor(sq, 1);
    sm += __shfl_xor(sm, 2); sq += __shfl_xor(sq, 2);
    sm += __shfl_xor(sm, 4); sq += __shfl_xor(sq, 4);
    sm += __shfl_xor(sm, 8); sq += __shfl_xor(sq, 8);
    float mu = sm / 128.0f;
    float var = sq / 128.0f - mu * mu;
    if (var < 0.f) var = 0.f;
    float ri = rsqrtf(var + 1e-6f);
    #pragma unroll
    for (int u = 0; u < 8; u++) {
      int c = q * 8 + u;
      s[(size_t)(nb + node) * 128 + c] = (bout[node][c] - mu) * ri * g_s[c] + b_s[c];
    }
  }
  __syncthreads();
  {
    int dd = tid & 63, ng = tid >> 6;
    float acc[4][3];
    #pragma unroll
    for (int n = 0; n < 4; n++)
      #pragma unroll
      for (int i = 0; i < 3; i++)
        acc[n][i] = v[(size_t)(nb + ng * 4 + n) * 192 + dd * 3 + i];
    for (int c = 0; c < 64; c++) {
      float w = Wo_v[c * 64 + dd];
      #pragma unroll
      for (int n = 0; n < 4; n++) {
        acc[n][0] += bin[ng * 4 + n][c * 3 + 0] * w;
        acc[n][1] += bin[ng * 4 + n][c * 3 + 1] * w;
        acc[n][2] += bin[ng * 4 + n][c * 3 + 2] * w;
      }
    }
    __syncthreads();
    #pragma unroll
    for (int n = 0; n < 4; n++)
      #pragma unroll
      for (int i = 0; i < 3; i++) bout[ng * 4 + n][dd * 3 + i] = acc[n][i];
  }
  __syncthreads();
  for (int idx = tid; idx < 16 * 160; idx += 256) {
    int n = idx / 160, c = idx % 160;
    bin[n][c] = agg_t[(size_t)(nb + n) * 160 + c];
  }
  {
    int node = tid >> 4, q = tid & 15;
    float ssq = 0.f;
    #pragma unroll
    for (int u = 0; u < 12; u++) {
      float x = bout[node][q * 12 + u];
      ssq += x * x;
    }
    ssq += __shfl_xor(ssq, 1);
    ssq += __shfl_xor(ssq, 2);
    ssq += __shfl_xor(ssq, 4);
    ssq += __shfl_xor(ssq, 8);
    float ri = rsqrtf(ssq / 64.0f + 1e-6f);
    #pragma unroll
    for (int u = 0; u < 12; u++) {
      int o = q * 12 + u;
      v[(size_t)(nb + node) * 192 + o] = bout[node][o] * ri * g_v[o / 3];
    }
  }
  __syncthreads();
  {
    int dd = tid & 31, ng = tid >> 5;
    float acc[2][5];
    #pragma unroll
    for (int n = 0; n < 2; n++)
      #pragma unroll
      for (int m = 0; m < 5; m++)
        acc[n][m] = t[(size_t)(nb + ng * 2 + n) * 160 + dd * 5 + m];
    for (int c = 0; c < 32; c++) {
      float w = Wo_t[c * 32 + dd];
      #pragma unroll
      for (int n = 0; n < 2; n++)
        #pragma unroll
        for (int m = 0; m < 5; m++) acc[n][m] += bin[ng * 2 + n][c * 5 + m] * w;
    }
    __syncthreads();
    #pragma unroll
    for (int n = 0; n < 2; n++)
      #pragma unroll
      for (int m = 0; m < 5; m++) bout[ng * 2 + n][dd * 5 + m] = acc[n][m];
  }
  __syncthreads();
  {
    int node = tid >> 4, q = tid & 15;
    float ssq = 0.f;
    #pragma unroll
    for (int u = 0; u < 10; u++) {
      float x = bout[node][q * 10 + u];
      ssq += x * x;
    }
    ssq += __shfl_xor(ssq, 1);
    ssq += __shfl_xor(ssq, 2);
    ssq += __shfl_xor(ssq, 4);
    ssq += __shfl_xor(ssq, 8);
    float ri = rsqrtf(ssq / 32.0f + 1e-6f);
    #pragma unroll
    for (int u = 0; u < 10; u++) {
      int o = q * 10 + u;
      t[(size_t)(nb + node) * 160 + o] = bout[node][o] * ri * g_t[o / 5];
    }
  }
}

// ---------------- readout (conflict-free mapping, batch via nperm) ----------------
__global__ __launch_bounds__(256) void k_readout(
    const float* __restrict__ s, const int* __restrict__ batch,
    const int* __restrict__ nperm,
    const float* __restrict__ W_feat, const float* __restrict__ b_feat,
    const float* __restrict__ W_out1, const float* __restrict__ b_out1,
    float* __restrict__ graph) {
  __shared__ float st[64][129];
  __shared__ float gacc[GG];
  int nb = blockIdx.x * 64;
  int fb = blockIdx.y;  // 0..7
  for (int idx = threadIdx.x; idx < 64 * 128; idx += 256) {
    int nl = idx >> 7, c = idx & 127;
    int n = nb + nl;
    st[nl][c] = (n < NN) ? s[(size_t)n * 128 + c] : 0.f;
  }
  if (threadIdx.x < GG) gacc[threadIdx.x] = 0.f;
  __syncthreads();
  int wv = threadIdx.x >> 6, lane = threadIdx.x & 63;
  int fg = lane & 15;
  int ns = lane >> 4;
  int f0 = fb * 64 + fg * 4;
  int nodeb = wv * 16 + ns * 4;
  float acc[4][4];
  #pragma unroll
  for (int nn = 0; nn < 4; nn++)
    #pragma unroll
    for (int k = 0; k < 4; k++) acc[nn][k] = b_feat[f0 + k];
  #pragma unroll 4
  for (int c = 0; c < 128; c++) {
    float4 wq = *(const float4*)&W_feat[(size_t)c * 512 + f0];
    #pragma unroll
    for (int nn = 0; nn < 4; nn++) {
      float sv = st[nodeb + nn][c];
      acc[nn][0] += sv * wq.x;
      acc[nn][1] += sv * wq.y;
      acc[nn][2] += sv * wq.z;
      acc[nn][3] += sv * wq.w;
    }
  }
  float wo[4];
  #pragma unroll
  for (int k = 0; k < 4; k++) wo[k] = W_out1[f0 + k];
  float ep[4];
  #pragma unroll
  for (int nn = 0; nn < 4; nn++) {
    float p = 0.f;
    #pragma unroll
    for (int k = 0; k < 4; k++) p += fgelu(acc[nn][k]) * wo[k];
    ep[nn] = p;
  }
  #pragma unroll
  for (int mm = 1; mm < 16; mm <<= 1) {
    #pragma unroll
    for (int nn = 0; nn < 4; nn++) ep[nn] += __shfl_xor(ep[nn], mm);
  }
  if (fg == 0) {
    #pragma unroll
    for (int nn = 0; nn < 4; nn++) {
      int n = nb + nodeb + nn;
      if (n < NN) {
        float e = ep[nn];
        if (fb == 0) e += b_out1[0];
        atomicAdd(&gacc[batch[nperm[n]]], e);
      }
    }
  }
  __syncthreads();
  if (threadIdx.x < GG && gacc[threadIdx.x] != 0.f)
    atomicAdd(&graph[threadIdx.x], gacc[threadIdx.x]);
}

__global__ void k_finalize(const float* __restrict__ graph, const float* __restrict__ W_read,
                           const float* __restrict__ b_read, float* __restrict__ out) {
  int g = threadIdx.x;
  if (g < GG) out[g] = graph[g] * W_read[0] + b_read[0];
}

// ---------------- host ----------------
extern "C" void kernel_launch(void* const* d_in, const int* in_sizes, int n_in,
                              void* d_out, int out_size, void* d_ws, size_t ws_size,
                              hipStream_t stream) {
  const float* pos = (const float*)d_in[0];
  const int* node_atom = (const int*)d_in[1];
  const int* batch = (const int*)d_in[2];
  const int* esrc = (const int*)d_in[3];
  const int* edst = (const int*)d_in[4];
  const float* atom_emb = (const float*)d_in[5];
  const float* Wrad1 = (const float*)d_in[6];
  const float* brad1 = (const float*)d_in[7];
  const float* Wrad2 = (const float*)d_in[8];
  const float* brad2 = (const float*)d_in[9];
  const float* Ws_src = (const float*)d_in[10];
  const float* Ww_s = (const float*)d_in[11];
  const float* Ws_v = (const float*)d_in[12];
  const float* Ww_v = (const float*)d_in[13];
  const float* Wv_v = (const float*)d_in[14];
  const float* Ww_vv = (const float*)d_in[15];
  const float* Ws_t = (const float*)d_in[16];
  const float* Ww_t = (const float*)d_in[17];
  const float* Wt_t = (const float*)d_in[18];
  const float* Ww_tt = (const float*)d_in[19];
  const float* attn_a = (const float*)d_in[20];
  const float* Wo_s = (const float*)d_in[21];
  const float* Wo_v = (const float*)d_in[22];
  const float* Wo_t = (const float*)d_in[23];
  const float* g_s = (const float*)d_in[24];
  const float* b_s = (const float*)d_in[25];
  const float* g_v = (const float*)d_in[26];
  const float* g_t = (const float*)d_in[27];
  const float* W_feat = (const float*)d_in[28];
  const float* b_feat = (const float*)d_in[29];
  const float* W_out1 = (const float*)d_in[30];
  const float* b_out1 = (const float*)d_in[31];
  const float* W_read = (const float*)d_in[32];
  const float* b_read = (const float*)d_in[33];
  float* out = (float*)d_out;

  char* base = (char*)d_ws;
  size_t off = 0;
  auto alloc = [&](size_t bytes) -> char* {
    off = (off + 255) & ~(size_t)255;
    char* p = base + off;
    off += bytes;
    return p;
  };
  int* cell_cnt = (int*)alloc(NCELL * 4);
  int* cell_off = (int*)alloc((NCELL + 1) * 4);
  int* ccur = (int*)alloc(NCELL * 4);
  int* nperm = (int*)alloc(NN * 4);
  int* ninv = (int*)alloc(NN * 4);
  int* deg = (int*)alloc(NN * 4);
  int* row_off = (int*)alloc((NN + 1) * 4);
  int* cursor = (int*)alloc(NN * 4);
  int* perm = (int*)alloc((size_t)EE * 4);
  float* d_csr = (float*)alloc((size_t)EE * 4);
  int* acnt = (int*)alloc(NN * 4);
  int* act_off = (int*)alloc((NN + 1) * 4);
  int* act_idx = (int*)alloc((size_t)EE * 4);
  float* d_a = (float*)alloc((size_t)EE * 4);
  int* src_a = (int*)alloc((size_t)EE * 4);
  float* sh_a = (float*)alloc((size_t)EE * 8 * 4);
  float* wtab = (float*)alloc((size_t)LL * TABN * 64 * 4);
  float* gs_tab = (float*)alloc((size_t)LL * TABN * 128 * 4);
  float* gv_tab = (float*)alloc((size_t)LL * TABN * 128 * 4);
  float* gt_tab = (float*)alloc((size_t)LL * TABN * 64 * 4);
  float* s = (float*)alloc((size_t)NN * 128 * 4);
  float* v = (float*)alloc((size_t)NN * 192 * 4);
  float* t = (float*)alloc((size_t)NN * 160 * 4);
  float* sWsrc = (float*)alloc((size_t)NN * 128 * 4);
  float* sWv = (float*)alloc((size_t)NN * 64 * 4);
  float* sWt = (float*)alloc((size_t)NN * 32 * 4);
  float* vW = (float*)alloc((size_t)NN * 192 * 4);
  float* tW = (float*)alloc((size_t)NN * 160 * 4);
  float* agg_s = (float*)alloc((size_t)NN * 128 * 4);
  float* agg_v = (float*)alloc((size_t)NN * 192 * 4);
  float* agg_t = (float*)alloc((size_t)NN * 160 * 4);
  float* graph = (float*)alloc(GG * 4);

  hipMemsetAsync(cell_cnt, 0, NCELL * 4, stream);
  hipMemsetAsync(ccur, 0, NCELL * 4, stream);
  hipMemsetAsync(deg, 0, NN * 4, stream);
  hipMemsetAsync(cursor, 0, NN * 4, stream);
  hipMemsetAsync(graph, 0, GG * 4, stream);
  hipMemsetAsync(v, 0, (size_t)NN * 192 * 4, stream);
  hipMemsetAsync(t, 0, (size_t)NN * 160 * 4, stream);

  k_ncell<<<(NN + 255) / 256, 256, 0, stream>>>(pos, cell_cnt);
  k_scan<<<1, 1024, 0, stream>>>(cell_cnt, cell_off, NCELL);
  k_nscatter<<<(NN + 255) / 256, 256, 0, stream>>>(pos, cell_off, ccur, nperm, ninv);
  k_hist<<<(EE + 255) / 256, 256, 0, stream>>>(edst, ninv, deg);
  k_scan<<<1, 1024, 0, stream>>>(deg, row_off, NN);
  k_scatter<<<(EE + 255) / 256, 256, 0, stream>>>(edst, ninv, row_off, cursor, perm);
  k_geom_d<<<(EE + 255) / 256, 256, 0, stream>>>(pos, esrc, edst, perm, d_csr);
  k_act_cnt<<<(NN + 255) / 256, 256, 0, stream>>>(row_off, d_csr, acnt);
  k_scan<<<1, 1024, 0, stream>>>(acnt, act_off, NN);
  k_act_fill<<<(NN + 255) / 256, 256, 0, stream>>>(row_off, d_csr, act_off, act_idx);
  k_geom_act<<<(EE + 255) / 256, 256, 0, stream>>>(act_idx, perm, esrc, edst, ninv, pos,
                                                   act_off, d_a, src_a, sh_a);
  k_build_wtab<<<LL * TABB, 256, 0, stream>>>(Wrad1, brad1, Wrad2, brad2, wtab);
  k_build_gs<<<LL * TABB, 256, 0, stream>>>(wtab, Ww_s, gs_tab);
  k_build_gv<<<LL * TABB, 256, 0, stream>>>(wtab, Ww_v, Ww_vv, gv_tab);
  k_build_gt<<<LL * TABB, 256, 0, stream>>>(wtab, Ww_t, Ww_tt, gt_tab);
  k_init_s<<<(NN * 128 + 255) / 256, 256, 0, stream>>>(node_atom, nperm, atom_emb, s);

  int megaGrid = 8 * ((CHUNK + 3) / 4);
  for (int l = 0; l < LL; l++) {
    const float* gsL = gs_tab + (size_t)l * TABN * 128;
    const float* gvL = gv_tab + (size_t)l * TABN * 128;
    const float* gtL = gt_tab + (size_t)l * TABN * 64;
    k_node_tf<<<NN / 16, 256, 0, stream>>>(
        s, v, t, Ws_src + (size_t)l * 128 * 128, Ws_v + (size_t)l * 128 * 64,
        Ws_t + (size_t)l * 128 * 32, Wv_v + (size_t)l * 64 * 64, Wt_t + (size_t)l * 32 * 32,
        sWsrc, sWv, sWt, vW, tW);
    k_mega<<<megaGrid, 256, 0, stream>>>(row_off, act_off, src_a, d_a, gsL, gvL, gtL,
                                         attn_a + (size_t)l * 128,
                                         sWsrc, sWv, sWt, vW, tW, sh_a, agg_s, agg_v, agg_t);
    k_node_up<<<NN / 16, 256, 0, stream>>>(s, v, t, agg_s, agg_v, agg_t,
                                           Wo_s + (size_t)l * 128 * 128,
                                           Wo_v + (size_t)l * 64 * 64, Wo_t + (size_t)l * 32 * 32,
                                           g_s + (size_t)l * 128, b_s + (size_t)l * 128,
                                           g_v + (size_t)l * 64, g_t + (size_t)l * 32);
  }
  dim3 rg((NN + 63) / 64, 8);
  k_readout<<<rg, 256, 0, stream>>>(s, batch, nperm, W_feat, b_feat, W_out1, b_out1, graph);
  k_finalize<<<1, 64, 0, stream>>>(graph, W_read, b_read, out);
}

// Round 14
// 1231.546 us; speedup vs baseline: 1.0938x; 1.0938x over previous
//
#include <hip/hip_runtime.h>
#include <math.h>

#define NN 10000
#define EE 320000
#define GG 32
#define LL 6
#define TABN 2048
#define TABB (TABN / 64)
#define DTAB 5.45f
#define DCUT 5.4f

__device__ __forceinline__ float fsilu(float x) { return x / (1.0f + __expf(-x)); }
__device__ __forceinline__ float fgelu(float x) {
  float y = 0.7978845608f * (x + 0.044715f * x * x * x);
  float t = 1.0f - 2.0f / (__expf(2.0f * y) + 1.0f);
  return 0.5f * x * (1.0f + t);
}

// ---------------- CSR build ----------------
__global__ void k_hist(const int* __restrict__ dst, int* __restrict__ deg) {
  int e = blockIdx.x * blockDim.x + threadIdx.x;
  if (e < EE) atomicAdd(&deg[dst[e]], 1);
}

__global__ void k_scan(const int* __restrict__ cnt, int* __restrict__ off, int n) {
  __shared__ int sm[1024];
  __shared__ int carry_s;
  if (threadIdx.x == 0) { carry_s = 0; off[0] = 0; }
  __syncthreads();
  for (int base = 0; base < n; base += 1024) {
    int i = base + (int)threadIdx.x;
    int v = (i < n) ? cnt[i] : 0;
    sm[threadIdx.x] = v;
    __syncthreads();
    for (int o = 1; o < 1024; o <<= 1) {
      int t = (threadIdx.x >= o) ? sm[threadIdx.x - o] : 0;
      __syncthreads();
      sm[threadIdx.x] += t;
      __syncthreads();
    }
    if (i < n) off[i + 1] = carry_s + sm[threadIdx.x];
    __syncthreads();
    if (threadIdx.x == 0) carry_s += sm[1023];
    __syncthreads();
  }
}

__global__ void k_scatter(const int* __restrict__ dst, const int* __restrict__ row_off,
                          int* __restrict__ cursor, int* __restrict__ perm) {
  int e = blockIdx.x * blockDim.x + threadIdx.x;
  if (e < EE) {
    int d = dst[e];
    int p = atomicAdd(&cursor[d], 1);
    perm[row_off[d] + p] = e;
  }
}

// ---------------- distances in CSR order ----------------
__global__ void k_geom_d(const float* __restrict__ pos, const int* __restrict__ esrc,
                         const int* __restrict__ edst, const int* __restrict__ perm,
                         float* __restrict__ d_csr) {
  int j = blockIdx.x * blockDim.x + threadIdx.x;
  if (j >= EE) return;
  int e = perm[j];
  int s = esrc[e], dd = edst[e];
  float rx = pos[dd * 3 + 0] - pos[s * 3 + 0];
  float ry = pos[dd * 3 + 1] - pos[s * 3 + 1];
  float rz = pos[dd * 3 + 2] - pos[s * 3 + 2];
  d_csr[j] = sqrtf(rx * rx + ry * ry + rz * rz + 1e-6f);
}

// ---------------- active-edge list (d < DCUT) ----------------
__global__ void k_act_cnt(const int* __restrict__ row_off, const float* __restrict__ d_csr,
                          int* __restrict__ acnt) {
  int n = blockIdx.x * blockDim.x + threadIdx.x;
  if (n >= NN) return;
  int c = 0;
  for (int j = row_off[n]; j < row_off[n + 1]; ++j) c += (d_csr[j] < DCUT) ? 1 : 0;
  acnt[n] = c;
}

__global__ void k_act_fill(const int* __restrict__ row_off, const float* __restrict__ d_csr,
                           const int* __restrict__ act_off, int* __restrict__ act_idx) {
  int n = blockIdx.x * blockDim.x + threadIdx.x;
  if (n >= NN) return;
  int a = act_off[n];
  for (int j = row_off[n]; j < row_off[n + 1]; ++j)
    if (d_csr[j] < DCUT) act_idx[a++] = j;
}

// ---------------- degree-descending scheduling order ----------------
__global__ void k_dhist(const int* __restrict__ acnt, int* __restrict__ dbkt) {
  int n = blockIdx.x * blockDim.x + threadIdx.x;
  if (n < NN) {
    int b = 127 - min(127, acnt[n]);
    atomicAdd(&dbkt[b], 1);
  }
}

__global__ void k_dscatter(const int* __restrict__ acnt, const int* __restrict__ dboff,
                           int* __restrict__ dbcur, int* __restrict__ order) {
  int n = blockIdx.x * blockDim.x + threadIdx.x;
  if (n < NN) {
    int b = 127 - min(127, acnt[n]);
    int p = atomicAdd(&dbcur[b], 1);
    order[dboff[b] + p] = n;
  }
}

// ---------------- compacted geometry per active edge ----------------
__global__ void k_geom_act(const int* __restrict__ act_idx, const int* __restrict__ perm,
                           const int* __restrict__ esrc, const int* __restrict__ edst,
                           const float* __restrict__ pos, const int* __restrict__ act_off,
                           float* __restrict__ d_a, int* __restrict__ src_a,
                           float* __restrict__ sh_a) {
  int a = blockIdx.x * blockDim.x + threadIdx.x;
  if (a >= act_off[NN]) return;
  int j = act_idx[a];
  int e = perm[j];
  int s = esrc[e], dd = edst[e];
  float rx = pos[dd * 3 + 0] - pos[s * 3 + 0];
  float ry = pos[dd * 3 + 1] - pos[s * 3 + 1];
  float rz = pos[dd * 3 + 2] - pos[s * 3 + 2];
  float d = sqrtf(rx * rx + ry * ry + rz * rz + 1e-6f);
  float inv = 1.0f / d;
  float x = rx * inv, y = ry * inv, z = rz * inv;
  d_a[a] = d;
  src_a[a] = s;
  const float s3 = 1.7320508075688772f;
  const float s5 = 2.23606797749979f;
  const float s15 = 3.872983346207417f;
  sh_a[a * 8 + 0] = s3 * x;
  sh_a[a * 8 + 1] = s3 * y;
  sh_a[a * 8 + 2] = s3 * z;
  sh_a[a * 8 + 3] = s15 * x * y;
  sh_a[a * 8 + 4] = s15 * y * z;
  sh_a[a * 8 + 5] = 0.5f * s5 * (3.0f * z * z - 1.0f);
  sh_a[a * 8 + 6] = s15 * x * z;
  sh_a[a * 8 + 7] = 0.5f * s15 * (x * x - y * y);
}

// ---------------- radial MLP table w(d) (all layers) ----------------
__global__ void k_build_wtab(const float* __restrict__ Wrad1, const float* __restrict__ brad1,
                             const float* __restrict__ Wrad2, const float* __restrict__ brad2,
                             float* __restrict__ wtab) {
  int l = blockIdx.x / TABB;
  int blk = blockIdx.x % TABB;
  __shared__ float W1[128 * 64];
  __shared__ float W2[64 * 64];
  __shared__ float b1[64], b2[64];
  __shared__ float rbf_s[4][128];
  __shared__ float h_s[4][64];
  const float* w1p = Wrad1 + (size_t)l * 128 * 64;
  const float* w2p = Wrad2 + (size_t)l * 64 * 64;
  for (int i = threadIdx.x; i < 128 * 64; i += 256) W1[i] = w1p[i];
  for (int i = threadIdx.x; i < 64 * 64; i += 256) W2[i] = w2p[i];
  if (threadIdx.x < 64) {
    b1[threadIdx.x] = brad1[(size_t)l * 64 + threadIdx.x];
    b2[threadIdx.x] = brad2[(size_t)l * 64 + threadIdx.x];
  }
  __syncthreads();
  int wv = threadIdx.x >> 6, lane = threadIdx.x & 63;
  const float width = 5.0f / 128.0f;
  for (int k = wv; k < 64; k += 4) {
    int i = blk * 64 + k;
    float d = (float)i * (DTAB / (float)(TABN - 1));
    float c0 = (5.0f * (float)lane) / 127.0f;
    float c1 = (5.0f * (float)(lane + 64)) / 127.0f;
    float t0 = (d - c0) / width, t1 = (d - c1) / width;
    rbf_s[wv][lane] = __expf(-0.5f * t0 * t0);
    rbf_s[wv][lane + 64] = __expf(-0.5f * t1 * t1);
    float acc = b1[lane];
    #pragma unroll 8
    for (int i2 = 0; i2 < 128; i2++) acc += rbf_s[wv][i2] * W1[i2 * 64 + lane];
    acc = fsilu(acc);
    h_s[wv][lane] = acc;
    float acc2 = b2[lane];
    #pragma unroll 8
    for (int i2 = 0; i2 < 64; i2++) acc2 += h_s[wv][i2] * W2[i2 * 64 + lane];
    wtab[((size_t)l * TABN + i) * 64 + lane] = fsilu(acc2);
  }
}

// ---------------- product tables: gs = w@Ww_s (128 cols) ----------------
__global__ __launch_bounds__(256) void k_build_gs(
    const float* __restrict__ wtab, const float* __restrict__ Ww_s,
    float* __restrict__ gs_tab) {
  int l = blockIdx.x / TABB, blk = blockIdx.x % TABB;
  __shared__ float W[64 * 128];
  __shared__ float ws[64][65];
  const float* wp = Ww_s + (size_t)l * 64 * 128;
  for (int i = threadIdx.x; i < 64 * 128; i += 256) W[i] = wp[i];
  const float* wt = wtab + ((size_t)l * TABN + blk * 64) * 64;
  for (int i = threadIdx.x; i < 64 * 64; i += 256) ws[i >> 6][i & 63] = wt[i];
  __syncthreads();
  int col = threadIdx.x & 127, eg = threadIdx.x >> 7;
  for (int e0 = 0; e0 < 64; e0 += 2) {
    int e = e0 + eg;
    float acc = 0.f;
    #pragma unroll 8
    for (int i = 0; i < 64; i++) acc += ws[e][i] * W[i * 128 + col];
    gs_tab[((size_t)l * TABN + blk * 64 + e) * 128 + col] = acc;
  }
}

// ---------------- product tables: gv pairs (w@Ww_v, w@Ww_vv) ----------------
__global__ __launch_bounds__(256) void k_build_gv(
    const float* __restrict__ wtab, const float* __restrict__ Ww_v,
    const float* __restrict__ Ww_vv, float* __restrict__ gv_tab) {
  int l = blockIdx.x / TABB, blk = blockIdx.x % TABB;
  __shared__ float W[64 * 128];  // interleaved pairs
  __shared__ float ws[64][65];
  const float* wv_p = Ww_v + (size_t)l * 64 * 64;
  const float* wvv_p = Ww_vv + (size_t)l * 64 * 64;
  for (int i = threadIdx.x; i < 64 * 128; i += 256) {
    int r = i >> 7, cc = i & 127;
    int c = cc >> 1;
    W[i] = (cc & 1) ? wvv_p[r * 64 + c] : wv_p[r * 64 + c];
  }
  const float* wt = wtab + ((size_t)l * TABN + blk * 64) * 64;
  for (int i = threadIdx.x; i < 64 * 64; i += 256) ws[i >> 6][i & 63] = wt[i];
  __syncthreads();
  int col = threadIdx.x & 127, eg = threadIdx.x >> 7;
  for (int e0 = 0; e0 < 64; e0 += 2) {
    int e = e0 + eg;
    float acc = 0.f;
    #pragma unroll 8
    for (int i = 0; i < 64; i++) acc += ws[e][i] * W[i * 128 + col];
    gv_tab[((size_t)l * TABN + blk * 64 + e) * 128 + col] = acc;
  }
}

// ---------------- product tables: gt pairs (w@Ww_t, w@Ww_tt) ----------------
__global__ __launch_bounds__(256) void k_build_gt(
    const float* __restrict__ wtab, const float* __restrict__ Ww_t,
    const float* __restrict__ Ww_tt, float* __restrict__ gt_tab) {
  int l = blockIdx.x / TABB, blk = blockIdx.x % TABB;
  __shared__ float W[64 * 64];  // interleaved pairs
  __shared__ float ws[64][65];
  const float* wt_p = Ww_t + (size_t)l * 64 * 32;
  const float* wtt_p = Ww_tt + (size_t)l * 64 * 32;
  for (int i = threadIdx.x; i < 64 * 64; i += 256) {
    int r = i >> 6, cc = i & 63;
    int c = cc >> 1;
    W[i] = (cc & 1) ? wtt_p[r * 32 + c] : wt_p[r * 32 + c];
  }
  const float* wt = wtab + ((size_t)l * TABN + blk * 64) * 64;
  for (int i = threadIdx.x; i < 64 * 64; i += 256) ws[i >> 6][i & 63] = wt[i];
  __syncthreads();
  int col = threadIdx.x & 63, eg = threadIdx.x >> 6;
  for (int e0 = 0; e0 < 64; e0 += 4) {
    int e = e0 + eg;
    float acc = 0.f;
    #pragma unroll 8
    for (int i = 0; i < 64; i++) acc += ws[e][i] * W[i * 64 + col];
    gt_tab[((size_t)l * TABN + blk * 64 + e) * 64 + col] = acc;
  }
}

// ---------------- init s ----------------
__global__ void k_init_s(const int* __restrict__ node_atom, const float* __restrict__ atom_emb,
                         float* __restrict__ s) {
  int i = blockIdx.x * blockDim.x + threadIdx.x;
  if (i < NN * 128) {
    int n = i >> 7, c = i & 127;
    s[i] = atom_emb[node_atom[n] * 128 + c];
  }
}

// ---------------- node transforms, 16 nodes/block ----------------
__global__ __launch_bounds__(256) void k_node_tf(
    const float* __restrict__ s, const float* __restrict__ v, const float* __restrict__ t,
    const float* __restrict__ Ws_src, const float* __restrict__ Ws_v,
    const float* __restrict__ Ws_t, const float* __restrict__ Wv_v,
    const float* __restrict__ Wt_t,
    float* __restrict__ sWsrc, float* __restrict__ sWv,
    float* __restrict__ sWt, float* __restrict__ vW, float* __restrict__ tW) {
  int nb = blockIdx.x * 16;
  int tid = threadIdx.x;
  __shared__ float s16[16][129];
  __shared__ float v16[16][192];
  __shared__ float t16[16][160];
  for (int idx = tid; idx < 16 * 128; idx += 256) {
    int n = idx >> 7, c = idx & 127;
    s16[n][c] = s[(size_t)(nb + n) * 128 + c];
  }
  for (int idx = tid; idx < 16 * 192; idx += 256) {
    int n = idx / 192, c = idx % 192;
    v16[n][c] = v[(size_t)(nb + n) * 192 + c];
  }
  for (int idx = tid; idx < 16 * 160; idx += 256) {
    int n = idx / 160, c = idx % 160;
    t16[n][c] = t[(size_t)(nb + n) * 160 + c];
  }
  __syncthreads();
  {
    int col = tid & 127, ng = tid >> 7;
    float acc[8] = {0, 0, 0, 0, 0, 0, 0, 0};
    for (int c = 0; c < 128; c++) {
      float w = Ws_src[c * 128 + col];
      #pragma unroll
      for (int n = 0; n < 8; n++) acc[n] += s16[ng * 8 + n][c] * w;
    }
    #pragma unroll
    for (int n = 0; n < 8; n++) sWsrc[(size_t)(nb + ng * 8 + n) * 128 + col] = acc[n];
  }
  {
    int col = tid & 63, ng = tid >> 6;
    float acc[4] = {0, 0, 0, 0};
    for (int c = 0; c < 128; c++) {
      float w = Ws_v[c * 64 + col];
      #pragma unroll
      for (int n = 0; n < 4; n++) acc[n] += s16[ng * 4 + n][c] * w;
    }
    #pragma unroll
    for (int n = 0; n < 4; n++) sWv[(size_t)(nb + ng * 4 + n) * 64 + col] = acc[n];
  }
  {
    int col = tid & 31, ng = tid >> 5;
    float acc[2] = {0, 0};
    for (int c = 0; c < 128; c++) {
      float w = Ws_t[c * 32 + col];
      acc[0] += s16[ng * 2 + 0][c] * w;
      acc[1] += s16[ng * 2 + 1][c] * w;
    }
    sWt[(size_t)(nb + ng * 2 + 0) * 32 + col] = acc[0];
    sWt[(size_t)(nb + ng * 2 + 1) * 32 + col] = acc[1];
  }
  {
    int dd = tid & 63, ng = tid >> 6;
    float acc[4][3] = {};
    for (int c = 0; c < 64; c++) {
      float w = Wv_v[c * 64 + dd];
      #pragma unroll
      for (int n = 0; n < 4; n++) {
        acc[n][0] += v16[ng * 4 + n][c * 3 + 0] * w;
        acc[n][1] += v16[ng * 4 + n][c * 3 + 1] * w;
        acc[n][2] += v16[ng * 4 + n][c * 3 + 2] * w;
      }
    }
    #pragma unroll
    for (int n = 0; n < 4; n++) {
      size_t b = (size_t)(nb + ng * 4 + n) * 192 + dd * 3;
      vW[b + 0] = acc[n][0];
      vW[b + 1] = acc[n][1];
      vW[b + 2] = acc[n][2];
    }
  }
  {
    int dd = tid & 31, ng = tid >> 5;
    float acc[2][5] = {};
    for (int c = 0; c < 32; c++) {
      float w = Wt_t[c * 32 + dd];
      #pragma unroll
      for (int n = 0; n < 2; n++)
        #pragma unroll
        for (int m = 0; m < 5; m++) acc[n][m] += t16[ng * 2 + n][c * 5 + m] * w;
    }
    #pragma unroll
    for (int n = 0; n < 2; n++) {
      size_t b = (size_t)(nb + ng * 2 + n) * 160 + dd * 5;
      #pragma unroll
      for (int m = 0; m < 5; m++) tW[b + m] = acc[n][m];
    }
  }
}

// ---------------- mega: single-pass online-softmax, edge-pair unrolled, degree-ordered ----------------
__global__ __launch_bounds__(256) void k_mega(
    const int* __restrict__ row_off, const int* __restrict__ act_off,
    const int* __restrict__ order,
    const int* __restrict__ src_a, const float* __restrict__ d_a,
    const float* __restrict__ gsL, const float* __restrict__ gvL,
    const float* __restrict__ gtL, const float* __restrict__ attn_l,
    const float* __restrict__ sWsrc, const float* __restrict__ sWv,
    const float* __restrict__ sWt, const float* __restrict__ vW,
    const float* __restrict__ tW, const float* __restrict__ sh_a,
    float* __restrict__ agg_s, float* __restrict__ agg_v, float* __restrict__ agg_t) {
  int wv = threadIdx.x >> 6, lane = threadIdx.x & 63;
  int lt = lane & 31;
  int slot = blockIdx.x * 4 + wv;
  if (slot >= NN) return;
  int n = order[slot];
  int alo = act_off[n], ahi = act_off[n + 1];
  int nact = ahi - alo;
  int ninact = (row_off[n + 1] - row_off[n]) - nact;
  const float sc = (float)(TABN - 1) / DTAB;
  float atnA = attn_l[lane];
  float atnB = attn_l[64 + lane];
  float rm0, rm1, rm2, rm3;
  rm0 = rm1 = rm2 = rm3 = (ninact > 0) ? 0.0f : -1e30f;
  float rs0 = 0.f, rs1 = 0.f, rs2 = 0.f, rs3 = 0.f;
  float as0 = 0.f, as1 = 0.f;
  float av0 = 0.f, av1 = 0.f, av2 = 0.f;
  float at0 = 0.f, at1 = 0.f, at2 = 0.f, at3 = 0.f, at4 = 0.f;
  int a = alo;
  for (; a + 1 < ahi; a += 2) {
    int aA = a, aB = a + 1;
    float dA = d_a[aA], dB = d_a[aB];
    int snA = src_a[aA], snB = src_a[aB];
    float xA = fminf(dA * sc, (float)(TABN - 1) - 1.0f);
    float xB = fminf(dB * sc, (float)(TABN - 1) - 1.0f);
    int iA = (int)xA, iB = (int)xB;
    float fA = xA - (float)iA, fB = xB - (float)iB;
    float g1A = 1.0f - fA, g1B = 1.0f - fB;
    const float* gA = gsL + (size_t)iA * 128;
    const float* gB = gsL + (size_t)iB * 128;
    float gsA_A = gA[lane] * g1A + gA[128 + lane] * fA;
    float gsB_A = gA[64 + lane] * g1A + gA[192 + lane] * fA;
    float gsA_B = gB[lane] * g1B + gB[128 + lane] * fB;
    float gsB_B = gB[64 + lane] * g1B + gB[192 + lane] * fB;
    float m0A = sWsrc[(size_t)snA * 128 + lane] * gsA_A;
    float m1A = sWsrc[(size_t)snA * 128 + 64 + lane] * gsB_A;
    float m0B = sWsrc[(size_t)snB * 128 + lane] * gsA_B;
    float m1B = sWsrc[(size_t)snB * 128 + 64 + lane] * gsB_B;
    const float* gvA = gvL + (size_t)iA * 128;
    const float* gvB = gvL + (size_t)iB * 128;
    float2 pA0 = *(const float2*)&gvA[2 * lane];
    float2 pA1 = *(const float2*)&gvA[128 + 2 * lane];
    float2 pB0 = *(const float2*)&gvB[2 * lane];
    float2 pB1 = *(const float2*)&gvB[128 + 2 * lane];
    float gavA = pA0.x * g1A + pA1.x * fA;
    float gbvA = pA0.y * g1A + pA1.y * fA;
    float gavB = pB0.x * g1B + pB1.x * fB;
    float gbvB = pB0.y * g1B + pB1.y * fB;
    float svA = sWv[(size_t)snA * 64 + lane];
    float svB = sWv[(size_t)snB * 64 + lane];
    float4 s1A = *(const float4*)&sh_a[(size_t)aA * 8];
    float4 s2A = *(const float4*)&sh_a[(size_t)aA * 8 + 4];
    float4 s1B = *(const float4*)&sh_a[(size_t)aB * 8];
    float4 s2B = *(const float4*)&sh_a[(size_t)aB * 8 + 4];
    const float* vpA = &vW[(size_t)snA * 192 + lane * 3];
    const float* vpB = &vW[(size_t)snB * 192 + lane * 3];
    float vA0 = vpA[0], vA1 = vpA[1], vA2 = vpA[2];
    float vB0 = vpB[0], vB1 = vpB[1], vB2 = vpB[2];
    float gatA = 0.f, gbtA = 0.f, gatB = 0.f, gbtB = 0.f;
    float stA = 0.f, stB = 0.f;
    float tA0 = 0.f, tA1 = 0.f, tA2 = 0.f, tA3 = 0.f, tA4 = 0.f;
    float tB0 = 0.f, tB1 = 0.f, tB2 = 0.f, tB3 = 0.f, tB4 = 0.f;
    if (lane < 32) {
      const float* gtA = gtL + (size_t)iA * 64;
      const float* gtB = gtL + (size_t)iB * 64;
      float2 qA0 = *(const float2*)&gtA[2 * lt];
      float2 qA1 = *(const float2*)&gtA[64 + 2 * lt];
      float2 qB0 = *(const float2*)&gtB[2 * lt];
      float2 qB1 = *(const float2*)&gtB[64 + 2 * lt];
      gatA = qA0.x * g1A + qA1.x * fA;
      gbtA = qA0.y * g1A + qA1.y * fA;
      gatB = qB0.x * g1B + qB1.x * fB;
      gbtB = qB0.y * g1B + qB1.y * fB;
      stA = sWt[(size_t)snA * 32 + lane];
      stB = sWt[(size_t)snB * 32 + lane];
      const float* tpA = &tW[(size_t)snA * 160 + lane * 5];
      const float* tpB = &tW[(size_t)snB * 160 + lane * 5];
      tA0 = tpA[0]; tA1 = tpA[1]; tA2 = tpA[2]; tA3 = tpA[3]; tA4 = tpA[4];
      tB0 = tpB[0]; tB1 = tpB[1]; tB2 = tpB[2]; tB3 = tpB[3]; tB4 = tpB[4];
    }
    float p01A = m0A * atnA, p23A = m1A * atnB;
    float p01B = m0B * atnA, p23B = m1B * atnB;
    #pragma unroll
    for (int mm = 1; mm < 32; mm <<= 1) {
      p01A += __shfl_xor(p01A, mm);
      p23A += __shfl_xor(p23A, mm);
      p01B += __shfl_xor(p01B, mm);
      p23B += __shfl_xor(p23B, mm);
    }
    float l0A = __shfl(p01A, 0), l1A = __shfl(p01A, 32);
    float l2A = __shfl(p23A, 0), l3A = __shfl(p23A, 32);
    float l0B = __shfl(p01B, 0), l1B = __shfl(p01B, 32);
    float l2B = __shfl(p23B, 0), l3B = __shfl(p23B, 32);
    {
      float nm0 = fmaxf(rm0, l0A), nm1 = fmaxf(rm1, l1A);
      float nm2 = fmaxf(rm2, l2A), nm3 = fmaxf(rm3, l3A);
      float f0 = __expf(rm0 - nm0), f1 = __expf(rm1 - nm1);
      float f2 = __expf(rm2 - nm2), f3 = __expf(rm3 - nm3);
      float w0 = __expf(l0A - nm0), w1 = __expf(l1A - nm1);
      float w2 = __expf(l2A - nm2), w3 = __expf(l3A - nm3);
      rm0 = nm0; rm1 = nm1; rm2 = nm2; rm3 = nm3;
      rs0 = rs0 * f0 + w0; rs1 = rs1 * f1 + w1;
      rs2 = rs2 * f2 + w2; rs3 = rs3 * f3 + w3;
      float fS0 = (lane < 32) ? f0 : f1;
      float fS1 = (lane < 32) ? f2 : f3;
      float wS0 = (lane < 32) ? w0 : w1;
      float wS1 = (lane < 32) ? w2 : w3;
      as0 = as0 * fS0 + wS0 * m0A;
      as1 = as1 * fS1 + wS1 * m1A;
      float fV = (lane < 16) ? f0 : (lane < 32) ? f1 : (lane < 48) ? f2 : f3;
      float wV = (lane < 16) ? w0 : (lane < 32) ? w1 : (lane < 48) ? w2 : w3;
      float avv = svA * gavA;
      av0 = av0 * fV + wV * (avv * s1A.x + vA0 * gbvA);
      av1 = av1 * fV + wV * (avv * s1A.y + vA1 * gbvA);
      av2 = av2 * fV + wV * (avv * s1A.z + vA2 * gbvA);
      if (lane < 32) {
        float fT = (lane < 8) ? f0 : (lane < 16) ? f1 : (lane < 24) ? f2 : f3;
        float wT = (lane < 8) ? w0 : (lane < 16) ? w1 : (lane < 24) ? w2 : w3;
        float att = stA * gatA;
        at0 = at0 * fT + wT * (att * s1A.w + tA0 * gbtA);
        at1 = at1 * fT + wT * (att * s2A.x + tA1 * gbtA);
        at2 = at2 * fT + wT * (att * s2A.y + tA2 * gbtA);
        at3 = at3 * fT + wT * (att * s2A.z + tA3 * gbtA);
        at4 = at4 * fT + wT * (att * s2A.w + tA4 * gbtA);
      }
    }
    {
      float nm0 = fmaxf(rm0, l0B), nm1 = fmaxf(rm1, l1B);
      float nm2 = fmaxf(rm2, l2B), nm3 = fmaxf(rm3, l3B);
      float f0 = __expf(rm0 - nm0), f1 = __expf(rm1 - nm1);
      float f2 = __expf(rm2 - nm2), f3 = __expf(rm3 - nm3);
      float w0 = __expf(l0B - nm0), w1 = __expf(l1B - nm1);
      float w2 = __expf(l2B - nm2), w3 = __expf(l3B - nm3);
      rm0 = nm0; rm1 = nm1; rm2 = nm2; rm3 = nm3;
      rs0 = rs0 * f0 + w0; rs1 = rs1 * f1 + w1;
      rs2 = rs2 * f2 + w2; rs3 = rs3 * f3 + w3;
      float fS0 = (lane < 32) ? f0 : f1;
      float fS1 = (lane < 32) ? f2 : f3;
      float wS0 = (lane < 32) ? w0 : w1;
      float wS1 = (lane < 32) ? w2 : w3;
      as0 = as0 * fS0 + wS0 * m0B;
      as1 = as1 * fS1 + wS1 * m1B;
      float fV = (lane < 16) ? f0 : (lane < 32) ? f1 : (lane < 48) ? f2 : f3;
      float wV = (lane < 16) ? w0 : (lane < 32) ? w1 : (lane < 48) ? w2 : w3;
      float avv = svB * gavB;
      av0 = av0 * fV + wV * (avv * s1B.x + vB0 * gbvB);
      av1 = av1 * fV + wV * (avv * s1B.y + vB1 * gbvB);
      av2 = av2 * fV + wV * (avv * s1B.z + vB2 * gbvB);
      if (lane < 32) {
        float fT = (lane < 8) ? f0 : (lane < 16) ? f1 : (lane < 24) ? f2 : f3;
        float wT = (lane < 8) ? w0 : (lane < 16) ? w1 : (lane < 24) ? w2 : w3;
        float att = stB * gatB;
        at0 = at0 * fT + wT * (att * s1B.w + tB0 * gbtB);
        at1 = at1 * fT + wT * (att * s2B.x + tB1 * gbtB);
        at2 = at2 * fT + wT * (att * s2B.y + tB2 * gbtB);
        at3 = at3 * fT + wT * (att * s2B.z + tB3 * gbtB);
        at4 = at4 * fT + wT * (att * s2B.w + tB4 * gbtB);
      }
    }
  }
  for (; a < ahi; ++a) {
    float x = d_a[a] * sc;
    x = fminf(x, (float)(TABN - 1) - 1.0f);
    int i0 = (int)x; float f = x - (float)i0; float g1 = 1.0f - f;
    int sn = src_a[a];
    const float* g0 = gsL + (size_t)i0 * 128;
    float gsA = g0[lane] * g1 + g0[128 + lane] * f;
    float gsB = g0[64 + lane] * g1 + g0[192 + lane] * f;
    float m0 = sWsrc[(size_t)sn * 128 + lane] * gsA;
    float m1 = sWsrc[(size_t)sn * 128 + 64 + lane] * gsB;
    float p01 = m0 * atnA;
    float p23 = m1 * atnB;
    #pragma unroll
    for (int mm = 1; mm < 32; mm <<= 1) {
      p01 += __shfl_xor(p01, mm);
      p23 += __shfl_xor(p23, mm);
    }
    float l0 = __shfl(p01, 0), l1 = __shfl(p01, 32);
    float l2 = __shfl(p23, 0), l3 = __shfl(p23, 32);
    float nm0 = fmaxf(rm0, l0), nm1 = fmaxf(rm1, l1);
    float nm2 = fmaxf(rm2, l2), nm3 = fmaxf(rm3, l3);
    float f0 = __expf(rm0 - nm0), f1 = __expf(rm1 - nm1);
    float f2 = __expf(rm2 - nm2), f3 = __expf(rm3 - nm3);
    float w0 = __expf(l0 - nm0), w1 = __expf(l1 - nm1);
    float w2 = __expf(l2 - nm2), w3 = __expf(l3 - nm3);
    rm0 = nm0; rm1 = nm1; rm2 = nm2; rm3 = nm3;
    rs0 = rs0 * f0 + w0; rs1 = rs1 * f1 + w1;
    rs2 = rs2 * f2 + w2; rs3 = rs3 * f3 + w3;
    float fS0 = (lane < 32) ? f0 : f1;
    float fS1 = (lane < 32) ? f2 : f3;
    float wS0 = (lane < 32) ? w0 : w1;
    float wS1 = (lane < 32) ? w2 : w3;
    as0 = as0 * fS0 + wS0 * m0;
    as1 = as1 * fS1 + wS1 * m1;
    const float* gv0 = gvL + (size_t)i0 * 128;
    float2 p0 = *(const float2*)&gv0[2 * lane];
    float2 p1 = *(const float2*)&gv0[128 + 2 * lane];
    float gav = p0.x * g1 + p1.x * f;
    float gbv = p0.y * g1 + p1.y * f;
    float fV = (lane < 16) ? f0 : (lane < 32) ? f1 : (lane < 48) ? f2 : f3;
    float wV = (lane < 16) ? w0 : (lane < 32) ? w1 : (lane < 48) ? w2 : w3;
    float avv = sWv[(size_t)sn * 64 + lane] * gav;
    float4 s1 = *(const float4*)&sh_a[(size_t)a * 8];
    float4 s2 = *(const float4*)&sh_a[(size_t)a * 8 + 4];
    const float* vp = &vW[(size_t)sn * 192 + lane * 3];
    av0 = av0 * fV + wV * (avv * s1.x + vp[0] * gbv);
    av1 = av1 * fV + wV * (avv * s1.y + vp[1] * gbv);
    av2 = av2 * fV + wV * (avv * s1.z + vp[2] * gbv);
    if (lane < 32) {
      const float* gt0 = gtL + (size_t)i0 * 64;
      float2 q0 = *(const float2*)&gt0[2 * lt];
      float2 q1 = *(const float2*)&gt0[64 + 2 * lt];
      float gat = q0.x * g1 + q1.x * f;
      float gbt = q0.y * g1 + q1.y * f;
      float fT = (lane < 8) ? f0 : (lane < 16) ? f1 : (lane < 24) ? f2 : f3;
      float wT = (lane < 8) ? w0 : (lane < 16) ? w1 : (lane < 24) ? w2 : w3;
      float att = sWt[(size_t)sn * 32 + lane] * gat;
      const float* tp = &tW[(size_t)sn * 160 + lane * 5];
      at0 = at0 * fT + wT * (att * s1.w + tp[0] * gbt);
      at1 = at1 * fT + wT * (att * s2.x + tp[1] * gbt);
      at2 = at2 * fT + wT * (att * s2.y + tp[2] * gbt);
      at3 = at3 * fT + wT * (att * s2.z + tp[3] * gbt);
      at4 = at4 * fT + wT * (att * s2.w + tp[4] * gbt);
    }
  }
  if (ninact > 0) {
    rs0 += (float)ninact * __expf(-rm0);
    rs1 += (float)ninact * __expf(-rm1);
    rs2 += (float)ninact * __expf(-rm2);
    rs3 += (float)ninact * __expf(-rm3);
  }
  float r0 = 1.0f / (rs0 + 1e-9f), r1 = 1.0f / (rs1 + 1e-9f);
  float r2 = 1.0f / (rs2 + 1e-9f), r3 = 1.0f / (rs3 + 1e-9f);
  float rS0 = (lane < 32) ? r0 : r1;
  float rS1 = (lane < 32) ? r2 : r3;
  float rV = (lane < 16) ? r0 : (lane < 32) ? r1 : (lane < 48) ? r2 : r3;
  agg_s[(size_t)n * 128 + lane] = as0 * rS0;
  agg_s[(size_t)n * 128 + 64 + lane] = as1 * rS1;
  agg_v[(size_t)n * 192 + lane * 3 + 0] = av0 * rV;
  agg_v[(size_t)n * 192 + lane * 3 + 1] = av1 * rV;
  agg_v[(size_t)n * 192 + lane * 3 + 2] = av2 * rV;
  if (lane < 32) {
    float rT = (lane < 8) ? r0 : (lane < 16) ? r1 : (lane < 24) ? r2 : r3;
    agg_t[(size_t)n * 160 + lane * 5 + 0] = at0 * rT;
    agg_t[(size_t)n * 160 + lane * 5 + 1] = at1 * rT;
    agg_t[(size_t)n * 160 + lane * 5 + 2] = at2 * rT;
    agg_t[(size_t)n * 160 + lane * 5 + 3] = at3 * rT;
    agg_t[(size_t)n * 160 + lane * 5 + 4] = at4 * rT;
  }
}

// ---------------- node update, 16 nodes/block, ping-pong LDS ----------------
__global__ __launch_bounds__(256) void k_node_up(
    float* __restrict__ s, float* __restrict__ v, float* __restrict__ t,
    const float* __restrict__ agg_s, const float* __restrict__ agg_v,
    const float* __restrict__ agg_t, const float* __restrict__ Wo_s,
    const float* __restrict__ Wo_v, const float* __restrict__ Wo_t,
    const float* __restrict__ g_s, const float* __restrict__ b_s,
    const float* __restrict__ g_v, const float* __restrict__ g_t) {
  int nb = blockIdx.x * 16;
  int tid = threadIdx.x;
  __shared__ float bin[16][193];
  __shared__ float bout[16][193];
  for (int idx = tid; idx < 16 * 128; idx += 256) {
    int n = idx >> 7, c = idx & 127;
    bin[n][c] = agg_s[(size_t)(nb + n) * 128 + c];
  }
  __syncthreads();
  {
    int col = tid & 127, ng = tid >> 7;
    float acc[8];
    #pragma unroll
    for (int n = 0; n < 8; n++) acc[n] = s[(size_t)(nb + ng * 8 + n) * 128 + col];
    for (int c = 0; c < 128; c++) {
      float w = Wo_s[c * 128 + col];
      #pragma unroll
      for (int n = 0; n < 8; n++) acc[n] += bin[ng * 8 + n][c] * w;
    }
    #pragma unroll
    for (int n = 0; n < 8; n++) bout[ng * 8 + n][col] = acc[n];
  }
  __syncthreads();
  for (int idx = tid; idx < 16 * 192; idx += 256) {
    int n = idx / 192, c = idx % 192;
    bin[n][c] = agg_v[(size_t)(nb + n) * 192 + c];
  }
  {
    int node = tid >> 4, q = tid & 15;
    float sm = 0.f, sq = 0.f;
    #pragma unroll
    for (int u = 0; u < 8; u++) {
      float x = bout[node][q * 8 + u];
      sm += x; sq += x * x;
    }
    sm += __shfl_xor(sm, 1); sq += __shfl_xor(sq, 1);
    sm += __shfl_xor(sm, 2); sq += __shfl_xor(sq, 2);
    sm += __shfl_xor(sm, 4); sq += __shfl_xor(sq, 4);
    sm += __shfl_xor(sm, 8); sq += __shfl_xor(sq, 8);
    float mu = sm / 128.0f;
    float var = sq / 128.0f - mu * mu;
    if (var < 0.f) var = 0.f;
    float ri = rsqrtf(var + 1e-6f);
    #pragma unroll
    for (int u = 0; u < 8; u++) {
      int c = q * 8 + u;
      s[(size_t)(nb + node) * 128 + c] = (bout[node][c] - mu) * ri * g_s[c] + b_s[c];
    }
  }
  __syncthreads();
  {
    int dd = tid & 63, ng = tid >> 6;
    float acc[4][3];
    #pragma unroll
    for (int n = 0; n < 4; n++)
      #pragma unroll
      for (int i = 0; i < 3; i++)
        acc[n][i] = v[(size_t)(nb + ng * 4 + n) * 192 + dd * 3 + i];
    for (int c = 0; c < 64; c++) {
      float w = Wo_v[c * 64 + dd];
      #pragma unroll
      for (int n = 0; n < 4; n++) {
        acc[n][0] += bin[ng * 4 + n][c * 3 + 0] * w;
        acc[n][1] += bin[ng * 4 + n][c * 3 + 1] * w;
        acc[n][2] += bin[ng * 4 + n][c * 3 + 2] * w;
      }
    }
    __syncthreads();
    #pragma unroll
    for (int n = 0; n < 4; n++)
      #pragma unroll
      for (int i = 0; i < 3; i++) bout[ng * 4 + n][dd * 3 + i] = acc[n][i];
  }
  __syncthreads();
  for (int idx = tid; idx < 16 * 160; idx += 256) {
    int n = idx / 160, c = idx % 160;
    bin[n][c] = agg_t[(size_t)(nb + n) * 160 + c];
  }
  {
    int node = tid >> 4, q = tid & 15;
    float ssq = 0.f;
    #pragma unroll
    for (int u = 0; u < 12; u++) {
      float x = bout[node][q * 12 + u];
      ssq += x * x;
    }
    ssq += __shfl_xor(ssq, 1);
    ssq += __shfl_xor(ssq, 2);
    ssq += __shfl_xor(ssq, 4);
    ssq += __shfl_xor(ssq, 8);
    float ri = rsqrtf(ssq / 64.0f + 1e-6f);
    #pragma unroll
    for (int u = 0; u < 12; u++) {
      int o = q * 12 + u;
      v[(size_t)(nb + node) * 192 + o] = bout[node][o] * ri * g_v[o / 3];
    }
  }
  __syncthreads();
  {
    int dd = tid & 31, ng = tid >> 5;
    float acc[2][5];
    #pragma unroll
    for (int n = 0; n < 2; n++)
      #pragma unroll
      for (int m = 0; m < 5; m++)
        acc[n][m] = t[(size_t)(nb + ng * 2 + n) * 160 + dd * 5 + m];
    for (int c = 0; c < 32; c++) {
      float w = Wo_t[c * 32 + dd];
      #pragma unroll
      for (int n = 0; n < 2; n++)
        #pragma unroll
        for (int m = 0; m < 5; m++) acc[n][m] += bin[ng * 2 + n][c * 5 + m] * w;
    }
    __syncthreads();
    #pragma unroll
    for (int n = 0; n < 2; n++)
      #pragma unroll
      for (int m = 0; m < 5; m++) bout[ng * 2 + n][dd * 5 + m] = acc[n][m];
  }
  __syncthreads();
  {
    int node = tid >> 4, q = tid & 15;
    float ssq = 0.f;
    #pragma unroll
    for (int u = 0; u < 10; u++) {
      float x = bout[node][q * 10 + u];
      ssq += x * x;
    }
    ssq += __shfl_xor(ssq, 1);
    ssq += __shfl_xor(ssq, 2);
    ssq += __shfl_xor(ssq, 4);
    ssq += __shfl_xor(ssq, 8);
    float ri = rsqrtf(ssq / 32.0f + 1e-6f);
    #pragma unroll
    for (int u = 0; u < 10; u++) {
      int o = q * 10 + u;
      t[(size_t)(nb + node) * 160 + o] = bout[node][o] * ri * g_t[o / 5];
    }
  }
}

// ---------------- readout (conflict-free mapping) ----------------
__global__ __launch_bounds__(256) void k_readout(
    const float* __restrict__ s, const int* __restrict__ batch,
    const float* __restrict__ W_feat, const float* __restrict__ b_feat,
    const float* __restrict__ W_out1, const float* __restrict__ b_out1,
    float* __restrict__ graph) {
  __shared__ float st[64][129];
  __shared__ float gacc[GG];
  int nb = blockIdx.x * 64;
  int fb = blockIdx.y;  // 0..7
  for (int idx = threadIdx.x; idx < 64 * 128; idx += 256) {
    int nl = idx >> 7, c = idx & 127;
    int n = nb + nl;
    st[nl][c] = (n < NN) ? s[(size_t)n * 128 + c] : 0.f;
  }
  if (threadIdx.x < GG) gacc[threadIdx.x] = 0.f;
  __syncthreads();
  int wv = threadIdx.x >> 6, lane = threadIdx.x & 63;
  int fg = lane & 15;
  int ns = lane >> 4;
  int f0 = fb * 64 + fg * 4;
  int nodeb = wv * 16 + ns * 4;
  float acc[4][4];
  #pragma unroll
  for (int nn = 0; nn < 4; nn++)
    #pragma unroll
    for (int k = 0; k < 4; k++) acc[nn][k] = b_feat[f0 + k];
  #pragma unroll 4
  for (int c = 0; c < 128; c++) {
    float4 wq = *(const float4*)&W_feat[(size_t)c * 512 + f0];
    #pragma unroll
    for (int nn = 0; nn < 4; nn++) {
      float sv = st[nodeb + nn][c];
      acc[nn][0] += sv * wq.x;
      acc[nn][1] += sv * wq.y;
      acc[nn][2] += sv * wq.z;
      acc[nn][3] += sv * wq.w;
    }
  }
  float wo[4];
  #pragma unroll
  for (int k = 0; k < 4; k++) wo[k] = W_out1[f0 + k];
  float ep[4];
  #pragma unroll
  for (int nn = 0; nn < 4; nn++) {
    float p = 0.f;
    #pragma unroll
    for (int k = 0; k < 4; k++) p += fgelu(acc[nn][k]) * wo[k];
    ep[nn] = p;
  }
  #pragma unroll
  for (int mm = 1; mm < 16; mm <<= 1) {
    #pragma unroll
    for (int nn = 0; nn < 4; nn++) ep[nn] += __shfl_xor(ep[nn], mm);
  }
  if (fg == 0) {
    #pragma unroll
    for (int nn = 0; nn < 4; nn++) {
      int n = nb + nodeb + nn;
      if (n < NN) {
        float e = ep[nn];
        if (fb == 0) e += b_out1[0];
        atomicAdd(&gacc[batch[n]], e);
      }
    }
  }
  __syncthreads();
  if (threadIdx.x < GG && gacc[threadIdx.x] != 0.f)
    atomicAdd(&graph[threadIdx.x], gacc[threadIdx.x]);
}

__global__ void k_finalize(const float* __restrict__ graph, const float* __restrict__ W_read,
                           const float* __restrict__ b_read, float* __restrict__ out) {
  int g = threadIdx.x;
  if (g < GG) out[g] = graph[g] * W_read[0] + b_read[0];
}

// ---------------- host ----------------
extern "C" void kernel_launch(void* const* d_in, const int* in_sizes, int n_in,
                              void* d_out, int out_size, void* d_ws, size_t ws_size,
                              hipStream_t stream) {
  const float* pos = (const float*)d_in[0];
  const int* node_atom = (const int*)d_in[1];
  const int* batch = (const int*)d_in[2];
  const int* esrc = (const int*)d_in[3];
  const int* edst = (const int*)d_in[4];
  const float* atom_emb = (const float*)d_in[5];
  const float* Wrad1 = (const float*)d_in[6];
  const float* brad1 = (const float*)d_in[7];
  const float* Wrad2 = (const float*)d_in[8];
  const float* brad2 = (const float*)d_in[9];
  const float* Ws_src = (const float*)d_in[10];
  const float* Ww_s = (const float*)d_in[11];
  const float* Ws_v = (const float*)d_in[12];
  const float* Ww_v = (const float*)d_in[13];
  const float* Wv_v = (const float*)d_in[14];
  const float* Ww_vv = (const float*)d_in[15];
  const float* Ws_t = (const float*)d_in[16];
  const float* Ww_t = (const float*)d_in[17];
  const float* Wt_t = (const float*)d_in[18];
  const float* Ww_tt = (const float*)d_in[19];
  const float* attn_a = (const float*)d_in[20];
  const float* Wo_s = (const float*)d_in[21];
  const float* Wo_v = (const float*)d_in[22];
  const float* Wo_t = (const float*)d_in[23];
  const float* g_s = (const float*)d_in[24];
  const float* b_s = (const float*)d_in[25];
  const float* g_v = (const float*)d_in[26];
  const float* g_t = (const float*)d_in[27];
  const float* W_feat = (const float*)d_in[28];
  const float* b_feat = (const float*)d_in[29];
  const float* W_out1 = (const float*)d_in[30];
  const float* b_out1 = (const float*)d_in[31];
  const float* W_read = (const float*)d_in[32];
  const float* b_read = (const float*)d_in[33];
  float* out = (float*)d_out;

  char* base = (char*)d_ws;
  size_t off = 0;
  auto alloc = [&](size_t bytes) -> char* {
    off = (off + 255) & ~(size_t)255;
    char* p = base + off;
    off += bytes;
    return p;
  };
  int* deg = (int*)alloc(NN * 4);
  int* row_off = (int*)alloc((NN + 1) * 4);
  int* cursor = (int*)alloc(NN * 4);
  int* perm = (int*)alloc((size_t)EE * 4);
  float* d_csr = (float*)alloc((size_t)EE * 4);
  int* acnt = (int*)alloc(NN * 4);
  int* act_off = (int*)alloc((NN + 1) * 4);
  int* act_idx = (int*)alloc((size_t)EE * 4);
  int* dbkt = (int*)alloc(128 * 4);
  int* dboff = (int*)alloc(129 * 4);
  int* dbcur = (int*)alloc(128 * 4);
  int* order = (int*)alloc(NN * 4);
  float* d_a = (float*)alloc((size_t)EE * 4);
  int* src_a = (int*)alloc((size_t)EE * 4);
  float* sh_a = (float*)alloc((size_t)EE * 8 * 4);
  float* wtab = (float*)alloc((size_t)LL * TABN * 64 * 4);
  float* gs_tab = (float*)alloc((size_t)LL * TABN * 128 * 4);
  float* gv_tab = (float*)alloc((size_t)LL * TABN * 128 * 4);
  float* gt_tab = (float*)alloc((size_t)LL * TABN * 64 * 4);
  float* s = (float*)alloc((size_t)NN * 128 * 4);
  float* v = (float*)alloc((size_t)NN * 192 * 4);
  float* t = (float*)alloc((size_t)NN * 160 * 4);
  float* sWsrc = (float*)alloc((size_t)NN * 128 * 4);
  float* sWv = (float*)alloc((size_t)NN * 64 * 4);
  float* sWt = (float*)alloc((size_t)NN * 32 * 4);
  float* vW = (float*)alloc((size_t)NN * 192 * 4);
  float* tW = (float*)alloc((size_t)NN * 160 * 4);
  float* agg_s = (float*)alloc((size_t)NN * 128 * 4);
  float* agg_v = (float*)alloc((size_t)NN * 192 * 4);
  float* agg_t = (float*)alloc((size_t)NN * 160 * 4);
  float* graph = (float*)alloc(GG * 4);

  hipMemsetAsync(deg, 0, NN * 4, stream);
  hipMemsetAsync(cursor, 0, NN * 4, stream);
  hipMemsetAsync(dbkt, 0, 128 * 4, stream);
  hipMemsetAsync(dbcur, 0, 128 * 4, stream);
  hipMemsetAsync(graph, 0, GG * 4, stream);
  hipMemsetAsync(v, 0, (size_t)NN * 192 * 4, stream);
  hipMemsetAsync(t, 0, (size_t)NN * 160 * 4, stream);

  k_hist<<<(EE + 255) / 256, 256, 0, stream>>>(edst, deg);
  k_scan<<<1, 1024, 0, stream>>>(deg, row_off, NN);
  k_scatter<<<(EE + 255) / 256, 256, 0, stream>>>(edst, row_off, cursor, perm);
  k_geom_d<<<(EE + 255) / 256, 256, 0, stream>>>(pos, esrc, edst, perm, d_csr);
  k_act_cnt<<<(NN + 255) / 256, 256, 0, stream>>>(row_off, d_csr, acnt);
  k_scan<<<1, 1024, 0, stream>>>(acnt, act_off, NN);
  k_act_fill<<<(NN + 255) / 256, 256, 0, stream>>>(row_off, d_csr, act_off, act_idx);
  k_dhist<<<(NN + 255) / 256, 256, 0, stream>>>(acnt, dbkt);
  k_scan<<<1, 1024, 0, stream>>>(dbkt, dboff, 128);
  k_dscatter<<<(NN + 255) / 256, 256, 0, stream>>>(acnt, dboff, dbcur, order);
  k_geom_act<<<(EE + 255) / 256, 256, 0, stream>>>(act_idx, perm, esrc, edst, pos, act_off,
                                                   d_a, src_a, sh_a);
  k_build_wtab<<<LL * TABB, 256, 0, stream>>>(Wrad1, brad1, Wrad2, brad2, wtab);
  k_build_gs<<<LL * TABB, 256, 0, stream>>>(wtab, Ww_s, gs_tab);
  k_build_gv<<<LL * TABB, 256, 0, stream>>>(wtab, Ww_v, Ww_vv, gv_tab);
  k_build_gt<<<LL * TABB, 256, 0, stream>>>(wtab, Ww_t, Ww_tt, gt_tab);
  k_init_s<<<(NN * 128 + 255) / 256, 256, 0, stream>>>(node_atom, atom_emb, s);

  for (int l = 0; l < LL; l++) {
    const float* gsL = gs_tab + (size_t)l * TABN * 128;
    const float* gvL = gv_tab + (size_t)l * TABN * 128;
    const float* gtL = gt_tab + (size_t)l * TABN * 64;
    k_node_tf<<<NN / 16, 256, 0, stream>>>(
        s, v, t, Ws_src + (size_t)l * 128 * 128, Ws_v + (size_t)l * 128 * 64,
        Ws_t + (size_t)l * 128 * 32, Wv_v + (size_t)l * 64 * 64, Wt_t + (size_t)l * 32 * 32,
        sWsrc, sWv, sWt, vW, tW);
    k_mega<<<NN / 4, 256, 0, stream>>>(row_off, act_off, order, src_a, d_a, gsL, gvL, gtL,
                                       attn_a + (size_t)l * 128,
                                       sWsrc, sWv, sWt, vW, tW, sh_a, agg_s, agg_v, agg_t);
    k_node_up<<<NN / 16, 256, 0, stream>>>(s, v, t, agg_s, agg_v, agg_t,
                                           Wo_s + (size_t)l * 128 * 128,
                                           Wo_v + (size_t)l * 64 * 64, Wo_t + (size_t)l * 32 * 32,
                                           g_s + (size_t)l * 128, b_s + (size_t)l * 128,
                                           g_v + (size_t)l * 64, g_t + (size_t)l * 32);
  }
  dim3 rg((NN + 63) / 64, 8);
  k_readout<<<rg, 256, 0, stream>>>(s, batch, W_feat, b_feat, W_out1, b_out1, graph);
  k_finalize<<<1, 64, 0, stream>>>(graph, W_read, b_read, out);
}